// Round 1
// baseline (8476.957 us; speedup 1.0000x reference)
//
#include <hip/hip_runtime.h>
#include <math.h>

// Dims (fixed by problem): B=16, S=1024, N=16384, DM=512, H=8, D=64, F=256, L=4
#define NTOK 16384
#define BATCH 16
#define SEQ 1024
#define DMODEL 512
#define NHEAD 8
#define HDIM 64
#define FDIM 256
#define SCALE_QK 0.3535533905932738f   // 64^-0.25
#define FSCALE 0.0625f                 // 256^-0.5

// ---------------------------------------------------------------- zero
__global__ void zero_kernel(float* __restrict__ p, int n) {
    int i = blockIdx.x * 256 + threadIdx.x;
    if (i < n) p[i] = 0.f;
}

// ---------------------------------------------------------------- encoder stage 1: mid = relu([x,pos]@w1 + b1)   [N,6]->[N,256]
__global__ __launch_bounds__(256) void enc1_kernel(
    const float* __restrict__ x, const float* __restrict__ pos,
    const float* __restrict__ w1, const float* __restrict__ b1,
    float* __restrict__ mid)
{
    int row = blockIdx.x, t = threadIdx.x;
    __shared__ float in6[6];
    if (t < 3) in6[t] = x[row * 3 + t];
    else if (t < 6) in6[t] = pos[row * 3 + (t - 3)];
    __syncthreads();
    float acc = b1[t];
#pragma unroll
    for (int j = 0; j < 6; j++) acc += in6[j] * w1[j * 256 + t];
    mid[(size_t)row * 256 + t] = fmaxf(acc, 0.f);
}

// ---------------------------------------------------------------- generic fp32 GEMM: C = [relu](A[M,K] @ W[K,Nc] + bias)
__global__ __launch_bounds__(256) void gemm_kernel(
    const float* __restrict__ A, const float* __restrict__ W,
    const float* __restrict__ bias, float* __restrict__ C,
    int M, int K, int Nc, int relu)
{
    __shared__ __align__(16) float As[16][68];
    __shared__ __align__(16) float Bs[16][68];
    int bm = blockIdx.y * 64, bn = blockIdx.x * 64;
    int tid = threadIdx.x;
    int tx = tid & 15, ty = tid >> 4;
    float acc[4][4] = {};
    int am = tid >> 2;            // 0..63
    int ak = (tid & 3) * 4;       // 0,4,8,12
    int bk = tid >> 4;            // 0..15
    int bn_c = (tid & 15) * 4;    // 0..60
    const float* Aptr = A + (size_t)(bm + am) * K + ak;
    const float* Wptr = W + (size_t)bk * Nc + bn + bn_c;

    for (int k0 = 0; k0 < K; k0 += 16) {
        float4 a4 = *(const float4*)(Aptr + k0);
        As[ak + 0][am] = a4.x; As[ak + 1][am] = a4.y;
        As[ak + 2][am] = a4.z; As[ak + 3][am] = a4.w;
        *(float4*)&Bs[bk][bn_c] = *(const float4*)(Wptr + (size_t)k0 * Nc);
        __syncthreads();
#pragma unroll
        for (int kk = 0; kk < 16; kk++) {
            float4 av = *(const float4*)&As[kk][ty * 4];
            float4 bv = *(const float4*)&Bs[kk][tx * 4];
            float a_[4] = {av.x, av.y, av.z, av.w};
            float b_[4] = {bv.x, bv.y, bv.z, bv.w};
#pragma unroll
            for (int i = 0; i < 4; i++)
#pragma unroll
                for (int j = 0; j < 4; j++)
                    acc[i][j] += a_[i] * b_[j];
        }
        __syncthreads();
    }
#pragma unroll
    for (int i = 0; i < 4; i++) {
        int m = bm + ty * 4 + i;
        float4 o;
        o.x = acc[i][0] + bias[bn + tx * 4 + 0];
        o.y = acc[i][1] + bias[bn + tx * 4 + 1];
        o.z = acc[i][2] + bias[bn + tx * 4 + 2];
        o.w = acc[i][3] + bias[bn + tx * 4 + 3];
        if (relu) {
            o.x = fmaxf(o.x, 0.f); o.y = fmaxf(o.y, 0.f);
            o.z = fmaxf(o.z, 0.f); o.w = fmaxf(o.w, 0.f);
        }
        *(float4*)(C + (size_t)m * Nc + bn + tx * 4) = o;
    }
}

// ---------------------------------------------------------------- residual + LayerNorm (row = 512)
__global__ __launch_bounds__(512) void add_ln_kernel(
    const float* __restrict__ res, const float* __restrict__ tin,
    const float* __restrict__ g, const float* __restrict__ bb,
    float* __restrict__ out)
{
    int row = blockIdx.x, t = threadIdx.x;
    size_t idx = (size_t)row * DMODEL + t;
    float val = tin[idx];
    if (res) val += res[idx];
    float s1 = val, s2 = val * val;
#pragma unroll
    for (int off = 32; off; off >>= 1) {
        s1 += __shfl_down(s1, off, 64);
        s2 += __shfl_down(s2, off, 64);
    }
    __shared__ float w1s[8], w2s[8];
    int wid = t >> 6, lane = t & 63;
    if (lane == 0) { w1s[wid] = s1; w2s[wid] = s2; }
    __syncthreads();
    if (t == 0) {
        float a1 = 0.f, a2 = 0.f;
#pragma unroll
        for (int i = 0; i < 8; i++) { a1 += w1s[i]; a2 += w2s[i]; }
        w1s[0] = a1 * (1.f / DMODEL);
        w2s[0] = a2 * (1.f / DMODEL);
    }
    __syncthreads();
    float m = w1s[0];
    float var = w2s[0] - m * m;
    float r = rsqrtf(var + 1e-5f);
    out[idx] = (val - m) * r * g[t] + bb[t];
}

// ---------------------------------------------------------------- FAVOR kv accumulate: kv[b,h,f,d] = sum_s phi(k)_f * v_d ; ksum[b,h,f]
// grid = B*H*4, block = 256 (thread = feature f)
__global__ __launch_bounds__(256) void favor_kv_kernel(
    const float* __restrict__ k, const float* __restrict__ v,
    const float* __restrict__ omega, float* __restrict__ kv,
    float* __restrict__ ksum)
{
    int bid = blockIdx.x;
    int chunk = bid & 3;
    int h = (bid >> 2) & 7;
    int b = bid >> 5;
    int tid = threadIdx.x;

    __shared__ float om[64 * 128];                    // 32KB
    __shared__ __align__(16) float kc[8][64];         // 2KB
    __shared__ __align__(16) float vc[8][64];         // 2KB
    __shared__ float hh[8];

    for (int i = tid; i < 64 * 128; i += 256) om[i] = omega[i];

    float4 kvacc4[16];
#pragma unroll
    for (int i = 0; i < 16; i++) kvacc4[i] = make_float4(0.f, 0.f, 0.f, 0.f);
    float ks_acc = 0.f;
    int fm = tid & 127;
    float sgn = (tid < 128) ? 1.f : -1.f;
    int s0 = chunk * 256;
    __syncthreads();

    for (int sc = 0; sc < 256; sc += 8) {
        {   // load 8 tokens of k (scaled) and v; compute hh per token
            int tt = tid >> 5, j = tid & 31;
            int s = s0 + sc + tt;
            const float2* kp = (const float2*)(k + ((size_t)(b * SEQ + s) * DMODEL) + h * HDIM);
            const float2* vp = (const float2*)(v + ((size_t)(b * SEQ + s) * DMODEL) + h * HDIM);
            float2 kvl = kp[j];
            float2 vvl = vp[j];
            float k0s = kvl.x * SCALE_QK, k1s = kvl.y * SCALE_QK;
            kc[tt][2 * j] = k0s; kc[tt][2 * j + 1] = k1s;
            vc[tt][2 * j] = vvl.x; vc[tt][2 * j + 1] = vvl.y;
            float p = k0s * k0s + k1s * k1s;
#pragma unroll
            for (int off = 16; off; off >>= 1) p += __shfl_down(p, off, 32);
            if (j == 0) hh[tt] = 0.5f * p;
        }
        __syncthreads();

        // u[t2] = dot(kc[t2], om[:,fm])
        float u[8];
#pragma unroll
        for (int t2 = 0; t2 < 8; t2++) u[t2] = 0.f;
#pragma unroll
        for (int dd4 = 0; dd4 < 16; dd4++) {
            float om0 = om[(4 * dd4 + 0) * 128 + fm];
            float om1 = om[(4 * dd4 + 1) * 128 + fm];
            float om2 = om[(4 * dd4 + 2) * 128 + fm];
            float om3 = om[(4 * dd4 + 3) * 128 + fm];
#pragma unroll
            for (int t2 = 0; t2 < 8; t2++) {
                float4 kc4 = *(const float4*)&kc[t2][dd4 * 4];
                u[t2] += kc4.x * om0 + kc4.y * om1 + kc4.z * om2 + kc4.w * om3;
            }
        }
        float phi[8];
#pragma unroll
        for (int t2 = 0; t2 < 8; t2++) {
            phi[t2] = expf(sgn * u[t2] - hh[t2]) * FSCALE;
            ks_acc += phi[t2];
        }
        // kvacc[d] += phi[t2] * vc[t2][d]
#pragma unroll
        for (int d4 = 0; d4 < 16; d4++) {
            float4 a4 = kvacc4[d4];
#pragma unroll
            for (int t2 = 0; t2 < 8; t2++) {
                float4 v4 = *(const float4*)&vc[t2][d4 * 4];
                a4.x += phi[t2] * v4.x; a4.y += phi[t2] * v4.y;
                a4.z += phi[t2] * v4.z; a4.w += phi[t2] * v4.w;
            }
            kvacc4[d4] = a4;
        }
        __syncthreads();
    }

    float* kvp = kv + ((size_t)((b * NHEAD + h) * FDIM + tid)) * HDIM;
#pragma unroll
    for (int d4 = 0; d4 < 16; d4++) {
        atomicAdd(&kvp[d4 * 4 + 0], kvacc4[d4].x);
        atomicAdd(&kvp[d4 * 4 + 1], kvacc4[d4].y);
        atomicAdd(&kvp[d4 * 4 + 2], kvacc4[d4].z);
        atomicAdd(&kvp[d4 * 4 + 3], kvacc4[d4].w);
    }
    atomicAdd(&ksum[(b * NHEAD + h) * FDIM + tid], ks_acc);
}

// ---------------------------------------------------------------- FAVOR attention apply:
// a[b,s,h,:] = z * phi(q) @ kv, z = 1/(phi(q)·ksum + eps)
// grid = B*H*64 (16-token chunks), block = 256
__global__ __launch_bounds__(256) void favor_attn_kernel(
    const float* __restrict__ q, const float* __restrict__ omega,
    const float* __restrict__ kv, const float* __restrict__ ksum,
    float* __restrict__ out)
{
    int bid = blockIdx.x;
    int chunk = bid & 63;
    int h = (bid >> 6) & 7;
    int b = bid >> 9;
    int s0 = chunk * 16;
    int tid = threadIdx.x;

    __shared__ float om[64 * 128];                 // 32KB
    __shared__ float phi_sh[16][256];              // 16KB
    __shared__ __align__(16) float qc[16][64];     // 4KB
    __shared__ float ks_sh[256];                   // 1KB
    __shared__ float hh[16], zz[16];

    for (int i = tid; i < 64 * 128; i += 256) om[i] = omega[i];
    ks_sh[tid] = ksum[(b * NHEAD + h) * FDIM + tid];

    {   // load 16 tokens of q (scaled), compute hh
        int tt = tid >> 4, j = tid & 15;
        const float4* qp = (const float4*)(q + ((size_t)(b * SEQ + s0 + tt) * DMODEL) + h * HDIM);
        float4 qv = qp[j];
        float v0 = qv.x * SCALE_QK, v1 = qv.y * SCALE_QK;
        float v2 = qv.z * SCALE_QK, v3 = qv.w * SCALE_QK;
        qc[tt][j * 4 + 0] = v0; qc[tt][j * 4 + 1] = v1;
        qc[tt][j * 4 + 2] = v2; qc[tt][j * 4 + 3] = v3;
        float p = v0 * v0 + v1 * v1 + v2 * v2 + v3 * v3;
#pragma unroll
        for (int off = 8; off; off >>= 1) p += __shfl_down(p, off, 16);
        if (j == 0) hh[tt] = 0.5f * p;
    }
    __syncthreads();

    // phase 1: features
    int fm = tid & 127;
    float sgn = (tid < 128) ? 1.f : -1.f;
    {
        float u[16];
#pragma unroll
        for (int tt = 0; tt < 16; tt++) u[tt] = 0.f;
#pragma unroll
        for (int dd4 = 0; dd4 < 16; dd4++) {
            float om0 = om[(4 * dd4 + 0) * 128 + fm];
            float om1 = om[(4 * dd4 + 1) * 128 + fm];
            float om2 = om[(4 * dd4 + 2) * 128 + fm];
            float om3 = om[(4 * dd4 + 3) * 128 + fm];
#pragma unroll
            for (int tt = 0; tt < 16; tt++) {
                float4 q4 = *(const float4*)&qc[tt][dd4 * 4];
                u[tt] += q4.x * om0 + q4.y * om1 + q4.z * om2 + q4.w * om3;
            }
        }
#pragma unroll
        for (int tt = 0; tt < 16; tt++)
            phi_sh[tt][tid] = expf(sgn * u[tt] - hh[tt]) * FSCALE;
    }
    __syncthreads();

    // z per token
    {
        int tt = tid >> 4, j = tid & 15;
        float p = 0.f;
#pragma unroll
        for (int i = 0; i < 16; i++) p += phi_sh[tt][j * 16 + i] * ks_sh[j * 16 + i];
#pragma unroll
        for (int off = 8; off; off >>= 1) p += __shfl_down(p, off, 16);
        if (j == 0) zz[tt] = 1.f / (p + 1e-6f);
    }

    // phase 2: out[d] = sum_f phi_f * kv[f][d] (split f over 4 groups)
    int g = tid >> 6, d = tid & 63;
    float part[16];
#pragma unroll
    for (int tt = 0; tt < 16; tt++) part[tt] = 0.f;
    const float* kvp = kv + (size_t)(b * NHEAD + h) * FDIM * HDIM;
    for (int f = g * 64; f < g * 64 + 64; f++) {
        float kvv = kvp[f * HDIM + d];
#pragma unroll
        for (int tt = 0; tt < 16; tt++) part[tt] += phi_sh[tt][f] * kvv;
    }
    __syncthreads();      // phi reads done; zz written
#pragma unroll
    for (int tt = 0; tt < 16; tt++) phi_sh[tt][tid] = part[tt];
    __syncthreads();

    // phase 3: reduce 4 groups, scale by z, store
#pragma unroll
    for (int r = 0; r < 4; r++) {
        int idx = tid + 256 * r;
        int tt = idx >> 6, dd = idx & 63;
        float sum = phi_sh[tt][dd] + phi_sh[tt][64 + dd] +
                    phi_sh[tt][128 + dd] + phi_sh[tt][192 + dd];
        out[((size_t)(b * SEQ + s0 + tt) * DMODEL) + h * HDIM + dd] = sum * zz[tt];
    }
}

// ---------------------------------------------------------------- pool + classify
__global__ __launch_bounds__(512) void pool_cls_kernel(
    const float* __restrict__ h, const float* __restrict__ cls_w,
    const float* __restrict__ cls_b, float* __restrict__ out)
{
    int b = blockIdx.x, t = threadIdx.x;
    float s = 0.f;
    for (int i = 0; i < SEQ; i++) s += h[((size_t)b * SEQ + i) * DMODEL + t];
    __shared__ float pooled[DMODEL];
    pooled[t] = s * (1.f / SEQ);
    __syncthreads();
    if (t < 16) {
        float acc = cls_b[t];
        for (int c = 0; c < DMODEL; c++) acc += pooled[c] * cls_w[c * 16 + t];
        out[b * 16 + t] = acc;
    }
}

// ----------------------------------------------------------------
extern "C" void kernel_launch(void* const* d_in, const int* in_sizes, int n_in,
                              void* d_out, int out_size, void* d_ws, size_t ws_size,
                              hipStream_t stream)
{
    const float* x      = (const float*)d_in[0];
    const float* pos    = (const float*)d_in[1];
    const float* enc_w1 = (const float*)d_in[2];
    const float* enc_b1 = (const float*)d_in[3];
    const float* enc_w2 = (const float*)d_in[4];
    const float* enc_b2 = (const float*)d_in[5];
    const float* enc_g  = (const float*)d_in[6];
    const float* enc_bb = (const float*)d_in[7];
    const float* wq = (const float*)d_in[8];
    const float* bq = (const float*)d_in[9];
    const float* wk = (const float*)d_in[10];
    const float* bk = (const float*)d_in[11];
    const float* wv = (const float*)d_in[12];
    const float* bv = (const float*)d_in[13];
    const float* wo = (const float*)d_in[14];
    const float* bo = (const float*)d_in[15];
    const float* ln1_g = (const float*)d_in[16];
    const float* ln1_b = (const float*)d_in[17];
    const float* w1 = (const float*)d_in[18];
    const float* b1 = (const float*)d_in[19];
    const float* w2 = (const float*)d_in[20];
    const float* b2 = (const float*)d_in[21];
    const float* ln2_g = (const float*)d_in[22];
    const float* ln2_b = (const float*)d_in[23];
    const float* omega = (const float*)d_in[24];
    const float* cls_w = (const float*)d_in[25];
    const float* cls_b = (const float*)d_in[26];
    float* out = (float*)d_out;

    const int N = NTOK;
    float* ws = (float*)d_ws;
    float* hbuf  = ws;
    float* qb    = hbuf  + (size_t)N * DMODEL;
    float* kb    = qb    + (size_t)N * DMODEL;
    float* vb    = kb    + (size_t)N * DMODEL;
    float* t512  = vb    + (size_t)N * DMODEL;
    float* t1024 = t512  + (size_t)N * DMODEL;
    float* kvb   = t1024 + (size_t)N * 1024;
    // ksum lives right after kv so one zero_kernel covers both
    const int KV_ELEMS = BATCH * NHEAD * FDIM * HDIM;        // 2097152
    const int KS_ELEMS = BATCH * NHEAD * FDIM;               // 32768
    float* ksb = kvb + KV_ELEMS;

    // ---- encoder ----
    enc1_kernel<<<N, 256, 0, stream>>>(x, pos, enc_w1, enc_b1, t1024);
    gemm_kernel<<<dim3(8, N / 64), 256, 0, stream>>>(t1024, enc_w2, enc_b2, t512, N, 256, 512, 0);
    add_ln_kernel<<<N, 512, 0, stream>>>(nullptr, t512, enc_g, enc_bb, hbuf);

    // ---- layers ----
    for (int l = 0; l < 4; l++) {
        const float* om_l = omega + (size_t)l * 64 * 128;
        gemm_kernel<<<dim3(8, N / 64), 256, 0, stream>>>(hbuf, wq + (size_t)l * DMODEL * DMODEL, bq + l * DMODEL, qb, N, 512, 512, 0);
        gemm_kernel<<<dim3(8, N / 64), 256, 0, stream>>>(hbuf, wk + (size_t)l * DMODEL * DMODEL, bk + l * DMODEL, kb, N, 512, 512, 0);
        gemm_kernel<<<dim3(8, N / 64), 256, 0, stream>>>(hbuf, wv + (size_t)l * DMODEL * DMODEL, bv + l * DMODEL, vb, N, 512, 512, 0);
        zero_kernel<<<(KV_ELEMS + KS_ELEMS + 255) / 256, 256, 0, stream>>>(kvb, KV_ELEMS + KS_ELEMS);
        favor_kv_kernel<<<BATCH * NHEAD * 4, 256, 0, stream>>>(kb, vb, om_l, kvb, ksb);
        favor_attn_kernel<<<BATCH * NHEAD * 64, 256, 0, stream>>>(qb, om_l, kvb, ksb, kb);
        gemm_kernel<<<dim3(8, N / 64), 256, 0, stream>>>(kb, wo + (size_t)l * DMODEL * DMODEL, bo + l * DMODEL, t512, N, 512, 512, 0);
        add_ln_kernel<<<N, 512, 0, stream>>>(hbuf, t512, ln1_g + l * DMODEL, ln1_b + l * DMODEL, hbuf);
        gemm_kernel<<<dim3(16, N / 64), 256, 0, stream>>>(hbuf, w1 + (size_t)l * DMODEL * 1024, b1 + l * 1024, t1024, N, 512, 1024, 1);
        gemm_kernel<<<dim3(8, N / 64), 256, 0, stream>>>(t1024, w2 + (size_t)l * 1024 * DMODEL, b2 + l * DMODEL, t512, N, 1024, 512, 0);
        add_ln_kernel<<<N, 512, 0, stream>>>(hbuf, t512, ln2_g + l * DMODEL, ln2_b + l * DMODEL, hbuf);
    }

    // ---- pool + classify ----
    pool_cls_kernel<<<BATCH, 512, 0, stream>>>(hbuf, cls_w, cls_b, out);
}

// Round 2
// 3742.685 us; speedup vs baseline: 2.2649x; 2.2649x over previous
//
#include <hip/hip_runtime.h>
#include <hip/hip_bf16.h>
#include <math.h>

// Dims (fixed): B=16, S=1024, N=16384, DM=512, H=8, D=64, F=256, L=4
#define NTOK 16384
#define BATCH 16
#define SEQ 1024
#define DMODEL 512
#define NHEAD 8
#define HDIM 64
#define FDIM 256
#define SCALE_QK 0.3535533905932738f   // 64^-0.25
#define FSCALE 0.0625f                 // 256^-0.5

typedef __bf16 bf16x8_t __attribute__((ext_vector_type(8)));
typedef float f32x4_t  __attribute__((ext_vector_type(4)));
typedef const __attribute__((address_space(1))) char* gas_t;
typedef __attribute__((address_space(3))) char* las_t;

__device__ __forceinline__ float b2f(unsigned short u) {
    union { unsigned int i; float f; } c; c.i = ((unsigned int)u) << 16; return c.f;
}
__device__ __forceinline__ unsigned short f2bu(float f) {
    __hip_bfloat16 h = __float2bfloat16(f);
    return *(unsigned short*)&h;
}

// ---------------------------------------------------------------- weight convert+transpose: W[K,N] f32 -> Wt[N,K] bf16
__global__ __launch_bounds__(256) void convT_kernel(
    const float* __restrict__ W, unsigned short* __restrict__ Wt, int K, int N)
{
    __shared__ float tile[32][33];
    int k0 = blockIdx.y * 32, n0 = blockIdx.x * 32;
    int t = threadIdx.x;
    int r = t >> 3, c4 = (t & 7) * 4;
    float4 v = *(const float4*)(W + (size_t)(k0 + r) * N + n0 + c4);
    tile[r][c4 + 0] = v.x; tile[r][c4 + 1] = v.y;
    tile[r][c4 + 2] = v.z; tile[r][c4 + 3] = v.w;
    __syncthreads();
    ushort4 o;
    o.x = f2bu(tile[c4 + 0][r]); o.y = f2bu(tile[c4 + 1][r]);
    o.z = f2bu(tile[c4 + 2][r]); o.w = f2bu(tile[c4 + 3][r]);
    *(ushort4*)(Wt + (size_t)(n0 + r) * K + k0 + c4) = o;
}

// ---------------------------------------------------------------- encoder stage 1: mid16 = relu([x,pos]@w1 + b1)  [N,6]->[N,256] bf16
__global__ __launch_bounds__(256) void enc1_kernel(
    const float* __restrict__ x, const float* __restrict__ pos,
    const float* __restrict__ w1, const float* __restrict__ b1,
    unsigned short* __restrict__ mid)
{
    int row = blockIdx.x, t = threadIdx.x;
    __shared__ float in6[6];
    if (t < 3) in6[t] = x[row * 3 + t];
    else if (t < 6) in6[t] = pos[row * 3 + (t - 3)];
    __syncthreads();
    float acc = b1[t];
#pragma unroll
    for (int j = 0; j < 6; j++) acc += in6[j] * w1[j * 256 + t];
    mid[(size_t)row * 256 + t] = f2bu(fmaxf(acc, 0.f));
}

// ---------------------------------------------------------------- bf16 MFMA GEMM: C = [relu](A[M,K] @ Bt[Nc,K]^T + bias)
// tile 128x128, BK=32, 4 waves (2x2), 4x4 16x16x32 frags per wave
template<int OUT_BF16, int RELU>
__global__ __launch_bounds__(256) void gemm_bf16_kernel(
    const unsigned short* __restrict__ A, const unsigned short* __restrict__ Bt,
    const float* __restrict__ bias, void* __restrict__ C,
    int M, int K, int Nc)
{
    __shared__ __align__(16) unsigned short As[128 * 32];
    __shared__ __align__(16) unsigned short Bs[128 * 32];
    const int tid = threadIdx.x;
    const int bm = blockIdx.y * 128, bn = blockIdx.x * 128;
    const int wave = tid >> 6, lane = tid & 63;
    const int wr = (wave >> 1) * 64, wc = (wave & 1) * 64;
    const int lm = lane & 15, lk = (lane >> 4) * 8;

    f32x4_t acc[4][4];
#pragma unroll
    for (int i = 0; i < 4; i++)
#pragma unroll
        for (int j = 0; j < 4; j++)
            acc[i][j] = (f32x4_t){0.f, 0.f, 0.f, 0.f};

    for (int k0 = 0; k0 < K; k0 += 32) {
#pragma unroll
        for (int it = 0; it < 2; ++it) {
            int t = tid + it * 256;
            const unsigned short* gp = A + (size_t)(bm + (t >> 2)) * K + k0 + (t & 3) * 8;
            __builtin_amdgcn_global_load_lds((gas_t)(const char*)gp,
                (las_t)((char*)As + t * 16), 16, 0, 0);
        }
#pragma unroll
        for (int it = 0; it < 2; ++it) {
            int t = tid + it * 256;
            const unsigned short* gp = Bt + (size_t)(bn + (t >> 2)) * K + k0 + (t & 3) * 8;
            __builtin_amdgcn_global_load_lds((gas_t)(const char*)gp,
                (las_t)((char*)Bs + t * 16), 16, 0, 0);
        }
        __syncthreads();
        bf16x8_t af[4], bfr[4];
#pragma unroll
        for (int i = 0; i < 4; i++)
            af[i] = *(const bf16x8_t*)(As + (size_t)(wr + 16 * i + lm) * 32 + lk);
#pragma unroll
        for (int j = 0; j < 4; j++)
            bfr[j] = *(const bf16x8_t*)(Bs + (size_t)(wc + 16 * j + lm) * 32 + lk);
#pragma unroll
        for (int i = 0; i < 4; i++)
#pragma unroll
            for (int j = 0; j < 4; j++)
                acc[i][j] = __builtin_amdgcn_mfma_f32_16x16x32_bf16(af[i], bfr[j], acc[i][j], 0, 0, 0);
        __syncthreads();
    }

    // C/D layout: col = lane&15, row = (lane>>4)*4 + reg   [verified m89/m91]
    const int col_l = lane & 15;
    const int row_q = (lane >> 4) * 4;
#pragma unroll
    for (int i = 0; i < 4; i++) {
#pragma unroll
        for (int j = 0; j < 4; j++) {
            int gn = bn + wc + 16 * j + col_l;
            float bsv = bias[gn];
            int gm0 = bm + wr + 16 * i + row_q;
#pragma unroll
            for (int r = 0; r < 4; r++) {
                float v = acc[i][j][r] + bsv;
                if (RELU) v = fmaxf(v, 0.f);
                if (OUT_BF16)
                    ((unsigned short*)C)[(size_t)(gm0 + r) * Nc + gn] = f2bu(v);
                else
                    ((float*)C)[(size_t)(gm0 + r) * Nc + gn] = v;
            }
        }
    }
}

// ---------------------------------------------------------------- residual + LayerNorm (row = 512), fp32 out + optional bf16 out
__global__ __launch_bounds__(512) void add_ln_kernel(
    const float* __restrict__ res, const float* __restrict__ tin,
    const float* __restrict__ g, const float* __restrict__ bb,
    float* __restrict__ out, unsigned short* __restrict__ out16)
{
    int row = blockIdx.x, t = threadIdx.x;
    size_t idx = (size_t)row * DMODEL + t;
    float val = tin[idx];
    if (res) val += res[idx];
    float s1 = val, s2 = val * val;
#pragma unroll
    for (int off = 32; off; off >>= 1) {
        s1 += __shfl_down(s1, off, 64);
        s2 += __shfl_down(s2, off, 64);
    }
    __shared__ float w1s[8], w2s[8];
    int wid = t >> 6, lane = t & 63;
    if (lane == 0) { w1s[wid] = s1; w2s[wid] = s2; }
    __syncthreads();
    if (t == 0) {
        float a1 = 0.f, a2 = 0.f;
#pragma unroll
        for (int i = 0; i < 8; i++) { a1 += w1s[i]; a2 += w2s[i]; }
        w1s[0] = a1 * (1.f / DMODEL);
        w2s[0] = a2 * (1.f / DMODEL);
    }
    __syncthreads();
    float m = w1s[0];
    float var = w2s[0] - m * m;
    float r = rsqrtf(var + 1e-5f);
    float y = (val - m) * r * g[t] + bb[t];
    out[idx] = y;
    if (out16) out16[idx] = f2bu(y);
}

// ---------------------------------------------------------------- FAVOR kv partials (no atomics): kvpart[chunk,b,h,f,d], kspart[chunk,b,h,f]
// grid = B*H*4, block = 256 (thread = feature f); k,v are bf16
__global__ __launch_bounds__(256) void favor_kv_kernel(
    const unsigned short* __restrict__ k, const unsigned short* __restrict__ v,
    const float* __restrict__ omega, float* __restrict__ kvpart,
    float* __restrict__ kspart)
{
    int bid = blockIdx.x;
    int chunk = bid & 3;
    int h = (bid >> 2) & 7;
    int b = bid >> 5;
    int tid = threadIdx.x;

    __shared__ float om[64 * 128];                    // 32KB
    __shared__ __align__(16) float kc[8][64];
    __shared__ __align__(16) float vc[8][64];
    __shared__ float hh[8];

    for (int i = tid; i < 64 * 128; i += 256) om[i] = omega[i];

    float4 kvacc4[16];
#pragma unroll
    for (int i = 0; i < 16; i++) kvacc4[i] = make_float4(0.f, 0.f, 0.f, 0.f);
    float ks_acc = 0.f;
    int fm = tid & 127;
    float sgn = (tid < 128) ? 1.f : -1.f;
    int s0 = chunk * 256;
    __syncthreads();

    for (int sc = 0; sc < 256; sc += 8) {
        {   // load 8 tokens of k (scaled) and v (bf16 -> f32); hh per token
            int tt = tid >> 5, j = tid & 31;
            int s = s0 + sc + tt;
            const unsigned short* kp = k + ((size_t)(b * SEQ + s) * DMODEL) + h * HDIM;
            const unsigned short* vp = v + ((size_t)(b * SEQ + s) * DMODEL) + h * HDIM;
            ushort2 kvl = *(const ushort2*)(kp + 2 * j);
            ushort2 vvl = *(const ushort2*)(vp + 2 * j);
            float k0s = b2f(kvl.x) * SCALE_QK, k1s = b2f(kvl.y) * SCALE_QK;
            kc[tt][2 * j] = k0s; kc[tt][2 * j + 1] = k1s;
            vc[tt][2 * j] = b2f(vvl.x); vc[tt][2 * j + 1] = b2f(vvl.y);
            float p = k0s * k0s + k1s * k1s;
#pragma unroll
            for (int off = 16; off; off >>= 1) p += __shfl_down(p, off, 32);
            if (j == 0) hh[tt] = 0.5f * p;
        }
        __syncthreads();

        float u[8];
#pragma unroll
        for (int t2 = 0; t2 < 8; t2++) u[t2] = 0.f;
#pragma unroll
        for (int dd4 = 0; dd4 < 16; dd4++) {
            float om0 = om[(4 * dd4 + 0) * 128 + fm];
            float om1 = om[(4 * dd4 + 1) * 128 + fm];
            float om2 = om[(4 * dd4 + 2) * 128 + fm];
            float om3 = om[(4 * dd4 + 3) * 128 + fm];
#pragma unroll
            for (int t2 = 0; t2 < 8; t2++) {
                float4 kc4 = *(const float4*)&kc[t2][dd4 * 4];
                u[t2] += kc4.x * om0 + kc4.y * om1 + kc4.z * om2 + kc4.w * om3;
            }
        }
        float phi[8];
#pragma unroll
        for (int t2 = 0; t2 < 8; t2++) {
            phi[t2] = expf(sgn * u[t2] - hh[t2]) * FSCALE;
            ks_acc += phi[t2];
        }
#pragma unroll
        for (int d4 = 0; d4 < 16; d4++) {
            float4 a4 = kvacc4[d4];
#pragma unroll
            for (int t2 = 0; t2 < 8; t2++) {
                float4 v4 = *(const float4*)&vc[t2][d4 * 4];
                a4.x += phi[t2] * v4.x; a4.y += phi[t2] * v4.y;
                a4.z += phi[t2] * v4.z; a4.w += phi[t2] * v4.w;
            }
            kvacc4[d4] = a4;
        }
        __syncthreads();
    }

    float* kvp = kvpart + (size_t)chunk * (BATCH * NHEAD * FDIM * HDIM)
               + ((size_t)((b * NHEAD + h) * FDIM + tid)) * HDIM;
#pragma unroll
    for (int d4 = 0; d4 < 16; d4++)
        *(float4*)(kvp + d4 * 4) = kvacc4[d4];
    kspart[(size_t)chunk * (BATCH * NHEAD * FDIM) + (b * NHEAD + h) * FDIM + tid] = ks_acc;
}

// ---------------------------------------------------------------- sum 4 partials
__global__ __launch_bounds__(256) void reduce4_kernel(
    const float* __restrict__ in, float* __restrict__ out, int n, int stride)
{
    int i = blockIdx.x * 256 + threadIdx.x;
    if (i < n)
        out[i] = in[i] + in[i + stride] + in[i + 2 * stride] + in[i + 3 * stride];
}

// ---------------------------------------------------------------- FAVOR attention apply (q bf16 in, bf16 out)
// grid = B*H*64 (16-token chunks), block = 256
__global__ __launch_bounds__(256) void favor_attn_kernel(
    const unsigned short* __restrict__ q, const float* __restrict__ omega,
    const float* __restrict__ kv, const float* __restrict__ ksum,
    unsigned short* __restrict__ out)
{
    int bid = blockIdx.x;
    int chunk = bid & 63;
    int h = (bid >> 6) & 7;
    int b = bid >> 9;
    int s0 = chunk * 16;
    int tid = threadIdx.x;

    __shared__ float om[64 * 128];                 // 32KB
    __shared__ float phi_sh[16][256];              // 16KB
    __shared__ __align__(16) float qc[16][64];     // 4KB
    __shared__ float ks_sh[256];
    __shared__ float hh[16], zz[16];

    for (int i = tid; i < 64 * 128; i += 256) om[i] = omega[i];
    ks_sh[tid] = ksum[(b * NHEAD + h) * FDIM + tid];

    {   // 16 tokens of q (bf16 -> f32, scaled), hh
        int tt = tid >> 4, j = tid & 15;
        const unsigned short* qp = q + ((size_t)(b * SEQ + s0 + tt) * DMODEL) + h * HDIM;
        ushort4 qv = *(const ushort4*)(qp + j * 4);
        float v0 = b2f(qv.x) * SCALE_QK, v1 = b2f(qv.y) * SCALE_QK;
        float v2 = b2f(qv.z) * SCALE_QK, v3 = b2f(qv.w) * SCALE_QK;
        qc[tt][j * 4 + 0] = v0; qc[tt][j * 4 + 1] = v1;
        qc[tt][j * 4 + 2] = v2; qc[tt][j * 4 + 3] = v3;
        float p = v0 * v0 + v1 * v1 + v2 * v2 + v3 * v3;
#pragma unroll
        for (int off = 8; off; off >>= 1) p += __shfl_down(p, off, 16);
        if (j == 0) hh[tt] = 0.5f * p;
    }
    __syncthreads();

    int fm = tid & 127;
    float sgn = (tid < 128) ? 1.f : -1.f;
    {
        float u[16];
#pragma unroll
        for (int tt = 0; tt < 16; tt++) u[tt] = 0.f;
#pragma unroll
        for (int dd4 = 0; dd4 < 16; dd4++) {
            float om0 = om[(4 * dd4 + 0) * 128 + fm];
            float om1 = om[(4 * dd4 + 1) * 128 + fm];
            float om2 = om[(4 * dd4 + 2) * 128 + fm];
            float om3 = om[(4 * dd4 + 3) * 128 + fm];
#pragma unroll
            for (int tt = 0; tt < 16; tt++) {
                float4 q4 = *(const float4*)&qc[tt][dd4 * 4];
                u[tt] += q4.x * om0 + q4.y * om1 + q4.z * om2 + q4.w * om3;
            }
        }
#pragma unroll
        for (int tt = 0; tt < 16; tt++)
            phi_sh[tt][tid] = expf(sgn * u[tt] - hh[tt]) * FSCALE;
    }
    __syncthreads();

    {   // z per token
        int tt = tid >> 4, j = tid & 15;
        float p = 0.f;
#pragma unroll
        for (int i = 0; i < 16; i++) p += phi_sh[tt][j * 16 + i] * ks_sh[j * 16 + i];
#pragma unroll
        for (int off = 8; off; off >>= 1) p += __shfl_down(p, off, 16);
        if (j == 0) zz[tt] = 1.f / (p + 1e-6f);
    }

    int g = tid >> 6, d = tid & 63;
    float part[16];
#pragma unroll
    for (int tt = 0; tt < 16; tt++) part[tt] = 0.f;
    const float* kvp = kv + (size_t)(b * NHEAD + h) * FDIM * HDIM;
    for (int f = g * 64; f < g * 64 + 64; f++) {
        float kvv = kvp[f * HDIM + d];
#pragma unroll
        for (int tt = 0; tt < 16; tt++) part[tt] += phi_sh[tt][f] * kvv;
    }
    __syncthreads();
#pragma unroll
    for (int tt = 0; tt < 16; tt++) phi_sh[tt][tid] = part[tt];
    __syncthreads();

#pragma unroll
    for (int r = 0; r < 4; r++) {
        int idx = tid + 256 * r;
        int tt = idx >> 6, dd = idx & 63;
        float sum = phi_sh[tt][dd] + phi_sh[tt][64 + dd] +
                    phi_sh[tt][128 + dd] + phi_sh[tt][192 + dd];
        out[((size_t)(b * SEQ + s0 + tt) * DMODEL) + h * HDIM + dd] = f2bu(sum * zz[tt]);
    }
}

// ---------------------------------------------------------------- pool + classify
__global__ __launch_bounds__(512) void pool_cls_kernel(
    const float* __restrict__ h, const float* __restrict__ cls_w,
    const float* __restrict__ cls_b, float* __restrict__ out)
{
    int b = blockIdx.x, t = threadIdx.x;
    float s = 0.f;
    for (int i = 0; i < SEQ; i++) s += h[((size_t)b * SEQ + i) * DMODEL + t];
    __shared__ float pooled[DMODEL];
    pooled[t] = s * (1.f / SEQ);
    __syncthreads();
    if (t < 16) {
        float acc = cls_b[t];
        for (int c = 0; c < DMODEL; c++) acc += pooled[c] * cls_w[c * 16 + t];
        out[b * 16 + t] = acc;
    }
}

// ----------------------------------------------------------------
static inline void launch_gemm(const unsigned short* A, const unsigned short* Bt,
                               const float* bias, void* C, int M, int K, int Nc,
                               int out_bf16, int relu, hipStream_t s)
{
    dim3 g(Nc / 128, M / 128);
    if (out_bf16) {
        if (relu) gemm_bf16_kernel<1, 1><<<g, 256, 0, s>>>(A, Bt, bias, C, M, K, Nc);
        else      gemm_bf16_kernel<1, 0><<<g, 256, 0, s>>>(A, Bt, bias, C, M, K, Nc);
    } else {
        gemm_bf16_kernel<0, 0><<<g, 256, 0, s>>>(A, Bt, bias, C, M, K, Nc);
    }
}

extern "C" void kernel_launch(void* const* d_in, const int* in_sizes, int n_in,
                              void* d_out, int out_size, void* d_ws, size_t ws_size,
                              hipStream_t stream)
{
    const float* x      = (const float*)d_in[0];
    const float* pos    = (const float*)d_in[1];
    const float* enc_w1 = (const float*)d_in[2];
    const float* enc_b1 = (const float*)d_in[3];
    const float* enc_w2 = (const float*)d_in[4];
    const float* enc_b2 = (const float*)d_in[5];
    const float* enc_g  = (const float*)d_in[6];
    const float* enc_bb = (const float*)d_in[7];
    const float* wq = (const float*)d_in[8];
    const float* bq = (const float*)d_in[9];
    const float* wk = (const float*)d_in[10];
    const float* bk = (const float*)d_in[11];
    const float* wv = (const float*)d_in[12];
    const float* bv = (const float*)d_in[13];
    const float* wo = (const float*)d_in[14];
    const float* bo = (const float*)d_in[15];
    const float* ln1_g = (const float*)d_in[16];
    const float* ln1_b = (const float*)d_in[17];
    const float* w1 = (const float*)d_in[18];
    const float* b1 = (const float*)d_in[19];
    const float* w2 = (const float*)d_in[20];
    const float* b2 = (const float*)d_in[21];
    const float* ln2_g = (const float*)d_in[22];
    const float* ln2_b = (const float*)d_in[23];
    const float* omega = (const float*)d_in[24];
    const float* cls_w = (const float*)d_in[25];
    const float* cls_b = (const float*)d_in[26];
    float* out = (float*)d_out;

    const int N = NTOK;
    const size_t KV_ELEMS = (size_t)BATCH * NHEAD * FDIM * HDIM;   // 2097152
    const size_t KS_ELEMS = (size_t)BATCH * NHEAD * FDIM;          // 32768

    char* p = (char*)d_ws;
    float* hbuf = (float*)p;            p += (size_t)N * DMODEL * 4;   // 32MB
    unsigned short* qb16 = (unsigned short*)p; p += (size_t)N * DMODEL * 2; // 16MB
    unsigned short* kb16 = (unsigned short*)p; p += (size_t)N * DMODEL * 2; // 16MB
    unsigned short* vb16 = (unsigned short*)p; p += (size_t)N * DMODEL * 2; // 16MB
    unsigned short* h16  = (unsigned short*)p; p += (size_t)N * DMODEL * 2; // 16MB
    unsigned short* mid16 = (unsigned short*)p; p += (size_t)N * 1024 * 2;  // 32MB
    unsigned short* attn16 = (unsigned short*)p; p += (size_t)N * DMODEL * 2; // 16MB
    float* kvpart = (float*)p;          p += KV_ELEMS * 4 * 4;         // 33.5MB
    float* kspart = (float*)p;          p += KS_ELEMS * 4 * 4;         // 0.5MB
    float* kvb = (float*)p;             p += KV_ELEMS * 4;             // 8.4MB
    float* ksb = (float*)p;             p += KS_ELEMS * 4;             // 0.13MB
    unsigned short* enc_w2t = (unsigned short*)p; p += (size_t)256 * 512 * 2;
    unsigned short* wqt = (unsigned short*)p; p += (size_t)4 * 512 * 512 * 2;
    unsigned short* wkt = (unsigned short*)p; p += (size_t)4 * 512 * 512 * 2;
    unsigned short* wvt = (unsigned short*)p; p += (size_t)4 * 512 * 512 * 2;
    unsigned short* wot = (unsigned short*)p; p += (size_t)4 * 512 * 512 * 2;
    unsigned short* w1t = (unsigned short*)p; p += (size_t)4 * 512 * 1024 * 2;
    unsigned short* w2t = (unsigned short*)p; p += (size_t)4 * 1024 * 512 * 2;
    // t512 aliases kb16+vb16 (dead by the time Wo/FFN2 write it)
    float* t512 = (float*)kb16;

    // ---- weight conversion (every launch; no persistent state allowed) ----
    convT_kernel<<<dim3(512 / 32, 256 / 32), 256, 0, stream>>>(enc_w2, enc_w2t, 256, 512);
    for (int l = 0; l < 4; l++) {
        convT_kernel<<<dim3(16, 16), 256, 0, stream>>>(wq + (size_t)l * 262144, wqt + (size_t)l * 262144, 512, 512);
        convT_kernel<<<dim3(16, 16), 256, 0, stream>>>(wk + (size_t)l * 262144, wkt + (size_t)l * 262144, 512, 512);
        convT_kernel<<<dim3(16, 16), 256, 0, stream>>>(wv + (size_t)l * 262144, wvt + (size_t)l * 262144, 512, 512);
        convT_kernel<<<dim3(16, 16), 256, 0, stream>>>(wo + (size_t)l * 262144, wot + (size_t)l * 262144, 512, 512);
        convT_kernel<<<dim3(32, 16), 256, 0, stream>>>(w1 + (size_t)l * 524288, w1t + (size_t)l * 524288, 512, 1024);
        convT_kernel<<<dim3(16, 32), 256, 0, stream>>>(w2 + (size_t)l * 524288, w2t + (size_t)l * 524288, 1024, 512);
    }

    // ---- encoder ----
    enc1_kernel<<<N, 256, 0, stream>>>(x, pos, enc_w1, enc_b1, mid16);
    launch_gemm(mid16, enc_w2t, enc_b2, t512, N, 256, 512, 0, 0, stream);
    add_ln_kernel<<<N, 512, 0, stream>>>(nullptr, t512, enc_g, enc_bb, hbuf, h16);

    // ---- layers ----
    for (int l = 0; l < 4; l++) {
        const float* om_l = omega + (size_t)l * 64 * 128;
        launch_gemm(h16, wqt + (size_t)l * 262144, bq + l * DMODEL, qb16, N, 512, 512, 1, 0, stream);
        launch_gemm(h16, wkt + (size_t)l * 262144, bk + l * DMODEL, kb16, N, 512, 512, 1, 0, stream);
        launch_gemm(h16, wvt + (size_t)l * 262144, bv + l * DMODEL, vb16, N, 512, 512, 1, 0, stream);
        favor_kv_kernel<<<BATCH * NHEAD * 4, 256, 0, stream>>>(kb16, vb16, om_l, kvpart, kspart);
        reduce4_kernel<<<(int)(KV_ELEMS / 256), 256, 0, stream>>>(kvpart, kvb, (int)KV_ELEMS, (int)KV_ELEMS);
        reduce4_kernel<<<(int)(KS_ELEMS / 256), 256, 0, stream>>>(kspart, ksb, (int)KS_ELEMS, (int)KS_ELEMS);
        favor_attn_kernel<<<BATCH * NHEAD * 64, 256, 0, stream>>>(qb16, om_l, kvb, ksb, attn16);
        launch_gemm(attn16, wot + (size_t)l * 262144, bo + l * DMODEL, t512, N, 512, 512, 0, 0, stream);
        add_ln_kernel<<<N, 512, 0, stream>>>(hbuf, t512, ln1_g + l * DMODEL, ln1_b + l * DMODEL, hbuf, h16);
        launch_gemm(h16, w1t + (size_t)l * 524288, b1 + l * 1024, mid16, N, 512, 1024, 1, 1, stream);
        launch_gemm(mid16, w2t + (size_t)l * 524288, b2 + l * DMODEL, t512, N, 1024, 512, 0, 0, stream);
        add_ln_kernel<<<N, 512, 0, stream>>>(hbuf, t512, ln2_g + l * DMODEL, ln2_b + l * DMODEL, hbuf, h16);
    }

    // ---- pool + classify ----
    pool_cls_kernel<<<BATCH, 512, 0, stream>>>(hbuf, cls_w, cls_b, out);
}

// Round 3
// 1573.372 us; speedup vs baseline: 5.3878x; 2.3788x over previous
//
#include <hip/hip_runtime.h>
#include <hip/hip_bf16.h>
#include <math.h>

// Dims (fixed): B=16, S=1024, N=16384, DM=512, H=8, D=64, F=256, L=4
#define NTOK 16384
#define BATCH 16
#define SEQ 1024
#define DMODEL 512
#define NHEAD 8
#define HDIM 64
#define FDIM 256
#define SCALE_QK 0.3535533905932738f   // 64^-0.25
#define SCALE2 0.125f                  // SCALE_QK^2
#define FSCALE 0.0625f                 // 256^-0.5

typedef __bf16 bf16x8_t __attribute__((ext_vector_type(8)));
typedef float f32x4_t  __attribute__((ext_vector_type(4)));
typedef unsigned short u16x8 __attribute__((ext_vector_type(8)));
typedef unsigned short u16x4 __attribute__((ext_vector_type(4)));
typedef const __attribute__((address_space(1))) char* gas_t;
typedef __attribute__((address_space(3))) char* las_t;

__device__ __forceinline__ float b2f(unsigned short u) {
    union { unsigned int i; float f; } c; c.i = ((unsigned int)u) << 16; return c.f;
}
__device__ __forceinline__ unsigned short f2bu(float f) {
    __hip_bfloat16 h = __float2bfloat16(f);
    return *(unsigned short*)&h;
}

// ---------------------------------------------------------------- zero
__global__ void zero_kernel(float* __restrict__ p, int n) {
    int i = blockIdx.x * 256 + threadIdx.x;
    if (i < n) p[i] = 0.f;
}

// ---------------------------------------------------------------- weight convert+transpose: W[K,N] f32 -> Wt[N,K] bf16
__global__ __launch_bounds__(256) void convT_kernel(
    const float* __restrict__ W, unsigned short* __restrict__ Wt, int K, int N)
{
    __shared__ float tile[32][33];
    int k0 = blockIdx.y * 32, n0 = blockIdx.x * 32;
    int t = threadIdx.x;
    int r = t >> 3, c4 = (t & 7) * 4;
    float4 v = *(const float4*)(W + (size_t)(k0 + r) * N + n0 + c4);
    tile[r][c4 + 0] = v.x; tile[r][c4 + 1] = v.y;
    tile[r][c4 + 2] = v.z; tile[r][c4 + 3] = v.w;
    __syncthreads();
    ushort4 o;
    o.x = f2bu(tile[c4 + 0][r]); o.y = f2bu(tile[c4 + 1][r]);
    o.z = f2bu(tile[c4 + 2][r]); o.w = f2bu(tile[c4 + 3][r]);
    *(ushort4*)(Wt + (size_t)(n0 + r) * K + k0 + c4) = o;
}

// ---------------------------------------------------------------- omega transpose+scale: om[L][64][128] f32 -> omT[L][128][64] bf16 * SCALE_QK
__global__ __launch_bounds__(256) void omT_kernel(
    const float* __restrict__ om, unsigned short* __restrict__ omT)
{
    int i = blockIdx.x * 256 + threadIdx.x;   // over 4*8192
    int l = i >> 13, rem = i & 8191;
    int f = rem >> 6, d = rem & 63;
    omT[(size_t)l * 8192 + f * 64 + d] = f2bu(om[(size_t)l * 8192 + d * 128 + f] * SCALE_QK);
}

// ---------------------------------------------------------------- encoder stage 1
__global__ __launch_bounds__(256) void enc1_kernel(
    const float* __restrict__ x, const float* __restrict__ pos,
    const float* __restrict__ w1, const float* __restrict__ b1,
    unsigned short* __restrict__ mid)
{
    int row = blockIdx.x, t = threadIdx.x;
    __shared__ float in6[6];
    if (t < 3) in6[t] = x[row * 3 + t];
    else if (t < 6) in6[t] = pos[row * 3 + (t - 3)];
    __syncthreads();
    float acc = b1[t];
#pragma unroll
    for (int j = 0; j < 6; j++) acc += in6[j] * w1[j * 256 + t];
    mid[(size_t)row * 256 + t] = f2bu(fmaxf(acc, 0.f));
}

// ---------------------------------------------------------------- bf16 MFMA GEMM: C = [relu](A[M,K] @ Bt[Nc,K]^T + bias)
// OUT_MODE: 0 = f32 rows, 1 = bf16 rows, 2 = bf16 per-head transposed [B,H,D,S] (Nc must be 512)
template<int OUT_MODE, int RELU>
__global__ __launch_bounds__(256) void gemm_bf16_kernel(
    const unsigned short* __restrict__ A, const unsigned short* __restrict__ Bt,
    const float* __restrict__ bias, void* __restrict__ C,
    int M, int K, int Nc)
{
    __shared__ __align__(16) unsigned short As[128 * 32];
    __shared__ __align__(16) unsigned short Bs[128 * 32];
    const int tid = threadIdx.x;
    const int bm = blockIdx.y * 128, bn = blockIdx.x * 128;
    const int wave = tid >> 6, lane = tid & 63;
    const int wr = (wave >> 1) * 64, wc = (wave & 1) * 64;
    const int lm = lane & 15, lk = (lane >> 4) * 8;

    f32x4_t acc[4][4];
#pragma unroll
    for (int i = 0; i < 4; i++)
#pragma unroll
        for (int j = 0; j < 4; j++)
            acc[i][j] = (f32x4_t){0.f, 0.f, 0.f, 0.f};

    for (int k0 = 0; k0 < K; k0 += 32) {
#pragma unroll
        for (int it = 0; it < 2; ++it) {
            int t = tid + it * 256;
            const unsigned short* gp = A + (size_t)(bm + (t >> 2)) * K + k0 + (t & 3) * 8;
            __builtin_amdgcn_global_load_lds((gas_t)(const char*)gp,
                (las_t)((char*)As + t * 16), 16, 0, 0);
        }
#pragma unroll
        for (int it = 0; it < 2; ++it) {
            int t = tid + it * 256;
            const unsigned short* gp = Bt + (size_t)(bn + (t >> 2)) * K + k0 + (t & 3) * 8;
            __builtin_amdgcn_global_load_lds((gas_t)(const char*)gp,
                (las_t)((char*)Bs + t * 16), 16, 0, 0);
        }
        __syncthreads();
        bf16x8_t af[4], bfr[4];
#pragma unroll
        for (int i = 0; i < 4; i++)
            af[i] = *(const bf16x8_t*)(As + (size_t)(wr + 16 * i + lm) * 32 + lk);
#pragma unroll
        for (int j = 0; j < 4; j++)
            bfr[j] = *(const bf16x8_t*)(Bs + (size_t)(wc + 16 * j + lm) * 32 + lk);
#pragma unroll
        for (int i = 0; i < 4; i++)
#pragma unroll
            for (int j = 0; j < 4; j++)
                acc[i][j] = __builtin_amdgcn_mfma_f32_16x16x32_bf16(af[i], bfr[j], acc[i][j], 0, 0, 0);
        __syncthreads();
    }

    const int col_l = lane & 15;
    const int row_q = (lane >> 4) * 4;
#pragma unroll
    for (int i = 0; i < 4; i++) {
#pragma unroll
        for (int j = 0; j < 4; j++) {
            int gn = bn + wc + 16 * j + col_l;
            float bsv = bias[gn];
            int gm0 = bm + wr + 16 * i + row_q;
            if (OUT_MODE == 2) {
                // vT[b,h,d,s] ; gm0 = b*1024+s ; gn = h*64+d ; gm0 % 4 == 0 within one b
                int bb_ = gm0 >> 10, ss = gm0 & 1023;
                int hh_ = gn >> 6, dd = gn & 63;
                u16x4 o4;
#pragma unroll
                for (int r = 0; r < 4; r++) o4[r] = f2bu(acc[i][j][r] + bsv);
                *(u16x4*)((unsigned short*)C +
                    (((size_t)(bb_ * NHEAD + hh_) * HDIM + dd) * SEQ + ss)) = o4;
            } else {
#pragma unroll
                for (int r = 0; r < 4; r++) {
                    float v = acc[i][j][r] + bsv;
                    if (RELU) v = fmaxf(v, 0.f);
                    if (OUT_MODE == 1)
                        ((unsigned short*)C)[(size_t)(gm0 + r) * Nc + gn] = f2bu(v);
                    else
                        ((float*)C)[(size_t)(gm0 + r) * Nc + gn] = v;
                }
            }
        }
    }
}

// ---------------------------------------------------------------- FAVOR feature kernel (MFMA): u = x @ omT^T, phi = exp(+-u - h)*FSCALE
// grid = B*H*(S/64); block 256 = 4 waves, each wave: 16 tokens x 128 feats
// IS_K=1: write phiT [B,H,F,S] + atomicAdd ksum[B,H,F]
// IS_K=0: write phiQ [B,H,S,F] + z[B,H,S] = 1/(phi . ksum + eps)
template<int IS_K>
__global__ __launch_bounds__(256) void feat_kernel(
    const unsigned short* __restrict__ X,    // [N, DM] bf16
    const unsigned short* __restrict__ omT,  // [128][64] bf16 (pre-scaled)
    unsigned short* __restrict__ phi_out,    // phiT or phiQ
    float* __restrict__ ksum,                // IS_K: accumulate ; else: read
    float* __restrict__ z)                   // IS_K=0 only
{
    const int bid = blockIdx.x;
    const int sc = bid & 15;
    const int h = (bid >> 4) & 7;
    const int b = bid >> 7;
    const int s0 = sc * 64;
    const int tid = threadIdx.x;

    __shared__ __align__(16) unsigned short xs[64 * 72];     // 9KB  [token][d] pad
    __shared__ __align__(16) unsigned short omTs[128 * 72];  // 18KB [f][d] pad
    __shared__ __align__(16) unsigned short phis[64 * 264];  // 33KB [token][f] pad
    __shared__ float hs[64];
    __shared__ float kss[256];

    // stage x tile (64 tokens x 64 d)
#pragma unroll
    for (int it = 0; it < 2; ++it) {
        int idx = tid + it * 256;
        int r = idx >> 3, c = (idx & 7) * 8;
        u16x8 v = *(const u16x8*)(X + (size_t)(b * SEQ + s0 + r) * DMODEL + h * HDIM + c);
        *(u16x8*)&xs[r * 72 + c] = v;
    }
    // stage omT (128 f x 64 d)
#pragma unroll
    for (int it = 0; it < 4; ++it) {
        int idx = tid + it * 256;
        int r = idx >> 3, c = (idx & 7) * 8;
        u16x8 v = *(const u16x8*)(omT + (size_t)r * 64 + c);
        *(u16x8*)&omTs[r * 72 + c] = v;
    }
    if (!IS_K) kss[tid] = ksum[(size_t)(b * NHEAD + h) * FDIM + tid];
    __syncthreads();

    // h_s = 0.5 * SCALE2 * sum_d x^2  (4 threads per token)
    {
        int token = tid >> 2, seg = (tid & 3) * 16;
        float p = 0.f;
#pragma unroll
        for (int j = 0; j < 16; j++) {
            float xv = b2f(xs[token * 72 + seg + j]);
            p += xv * xv;
        }
        p += __shfl_down(p, 2, 4);
        p += __shfl_down(p, 1, 4);
        if ((tid & 3) == 0) hs[token] = 0.5f * SCALE2 * p;
    }

    // MFMA: u[token][f]
    const int wave = tid >> 6, lane = tid & 63;
    const int m0 = wave * 16;
    const int lm = lane & 15, lk = (lane >> 4) * 8;
    f32x4_t acc[8];
#pragma unroll
    for (int j = 0; j < 8; j++) acc[j] = (f32x4_t){0.f, 0.f, 0.f, 0.f};
#pragma unroll
    for (int ks = 0; ks < 2; ks++) {
        bf16x8_t af = *(const bf16x8_t*)&xs[(m0 + lm) * 72 + ks * 32 + lk];
#pragma unroll
        for (int j = 0; j < 8; j++) {
            bf16x8_t bfr = *(const bf16x8_t*)&omTs[(j * 16 + lm) * 72 + ks * 32 + lk];
            acc[j] = __builtin_amdgcn_mfma_f32_16x16x32_bf16(af, bfr, acc[j], 0, 0, 0);
        }
    }
    __syncthreads();   // hs ready

    const int col_l = lane & 15;
    const int quad4 = (lane >> 4) * 4;
#pragma unroll
    for (int j = 0; j < 8; j++) {
        int f = j * 16 + col_l;
#pragma unroll
        for (int r = 0; r < 4; r++) {
            int m = m0 + quad4 + r;
            float u = acc[j][r];
            float hh = hs[m];
            phis[m * 264 + f]       = f2bu(__expf(u - hh) * FSCALE);
            phis[m * 264 + 128 + f] = f2bu(__expf(-u - hh) * FSCALE);
        }
    }
    __syncthreads();

    if (IS_K) {
        // thread = feature f: write phiT row (64 tokens) + ksum partial
        int f = tid;
        size_t base = ((size_t)(b * NHEAD + h) * FDIM + f) * SEQ + s0;
        float kp = 0.f;
#pragma unroll
        for (int mm = 0; mm < 64; mm += 8) {
            u16x8 v8;
#pragma unroll
            for (int jj = 0; jj < 8; jj++) {
                unsigned short pv = phis[(mm + jj) * 264 + f];
                v8[jj] = pv;
                kp += b2f(pv);
            }
            *(u16x8*)(phi_out + base + mm) = v8;
        }
        atomicAdd(&ksum[(size_t)(b * NHEAD + h) * FDIM + f], kp);
    } else {
        // thread: token m = tid>>2, feature quarter; write phiQ rows + z
        int m = tid >> 2, fp = (tid & 3) * 64;
        size_t base = ((size_t)(b * NHEAD + h) * SEQ + s0 + m) * FDIM + fp;
        float zp = 0.f;
#pragma unroll
        for (int jj = 0; jj < 64; jj += 8) {
            u16x8 v = *(const u16x8*)&phis[m * 264 + fp + jj];
            *(u16x8*)(phi_out + base + jj) = v;
#pragma unroll
            for (int e = 0; e < 8; e++) zp += b2f(v[e]) * kss[fp + jj + e];
        }
        zp += __shfl_down(zp, 2, 4);
        zp += __shfl_down(zp, 1, 4);
        if ((tid & 3) == 0)
            z[(size_t)(b * NHEAD + h) * SEQ + s0 + m] = 1.f / (zp + 1e-6f);
    }
}

// ---------------------------------------------------------------- kv GEMM: kvT[bh][d][f] = sum_s phiT[bh][f][s] * vT[bh][d][s]
// grid = B*H, block 256 = 4 waves, wave: 64 f-rows x 64 d
__global__ __launch_bounds__(256) void kv_kernel(
    const unsigned short* __restrict__ phiT,  // [BH, 256, 1024]
    const unsigned short* __restrict__ vT,    // [BH, 64, 1024]
    unsigned short* __restrict__ kvT)         // [BH, 64, 256]
{
    __shared__ __align__(16) unsigned short As[256 * 32];  // 16KB
    __shared__ __align__(16) unsigned short Bs[64 * 32];   // 4KB
    const int bh = blockIdx.x;
    const int tid = threadIdx.x;
    const int wave = tid >> 6, lane = tid & 63;
    const int wr = wave * 64;
    const int lm = lane & 15, lk = (lane >> 4) * 8;
    const unsigned short* Abase = phiT + (size_t)bh * FDIM * SEQ;
    const unsigned short* Bbase = vT + (size_t)bh * HDIM * SEQ;

    f32x4_t acc[4][4];
#pragma unroll
    for (int i = 0; i < 4; i++)
#pragma unroll
        for (int j = 0; j < 4; j++)
            acc[i][j] = (f32x4_t){0.f, 0.f, 0.f, 0.f};

    for (int k0 = 0; k0 < SEQ; k0 += 32) {
#pragma unroll
        for (int it = 0; it < 4; ++it) {
            int t = tid + it * 256;
            const unsigned short* gp = Abase + (size_t)(t >> 2) * SEQ + k0 + (t & 3) * 8;
            __builtin_amdgcn_global_load_lds((gas_t)(const char*)gp,
                (las_t)((char*)As + t * 16), 16, 0, 0);
        }
        {
            int t = tid;
            const unsigned short* gp = Bbase + (size_t)(t >> 2) * SEQ + k0 + (t & 3) * 8;
            __builtin_amdgcn_global_load_lds((gas_t)(const char*)gp,
                (las_t)((char*)Bs + t * 16), 16, 0, 0);
        }
        __syncthreads();
        bf16x8_t af[4], bfr[4];
#pragma unroll
        for (int i = 0; i < 4; i++)
            af[i] = *(const bf16x8_t*)(As + (size_t)(wr + 16 * i + lm) * 32 + lk);
#pragma unroll
        for (int j = 0; j < 4; j++)
            bfr[j] = *(const bf16x8_t*)(Bs + (size_t)(16 * j + lm) * 32 + lk);
#pragma unroll
        for (int i = 0; i < 4; i++)
#pragma unroll
            for (int j = 0; j < 4; j++)
                acc[i][j] = __builtin_amdgcn_mfma_f32_16x16x32_bf16(af[i], bfr[j], acc[i][j], 0, 0, 0);
        __syncthreads();
    }

    const int col_l = lane & 15;
    const int quad4 = (lane >> 4) * 4;
#pragma unroll
    for (int i = 0; i < 4; i++) {
#pragma unroll
        for (int j = 0; j < 4; j++) {
            int f0 = wr + 16 * i + quad4;       // row (feature), consecutive over r
            int d = 16 * j + col_l;             // col (head dim)
            u16x4 o4;
#pragma unroll
            for (int r = 0; r < 4; r++) o4[r] = f2bu(acc[i][j][r]);
            *(u16x4*)(kvT + (size_t)bh * HDIM * FDIM + (size_t)d * FDIM + f0) = o4;
        }
    }
}

// ---------------------------------------------------------------- attn GEMM: out[s, h*64+d] = z[s] * sum_f phiQ[s,f] * kvT[d,f]
// grid = B*H*8 (128-token chunks), block 256 = 4 waves (2x2), wave: 64 s x 32 d
__global__ __launch_bounds__(256) void attn_kernel(
    const unsigned short* __restrict__ phiQ,  // [BH, 1024, 256]
    const unsigned short* __restrict__ kvT,   // [BH, 64, 256]
    const float* __restrict__ z,              // [BH, 1024]
    unsigned short* __restrict__ outX)        // [N, DM]
{
    __shared__ __align__(16) unsigned short As[128 * 32];  // 8KB
    __shared__ __align__(16) unsigned short Bs[64 * 32];   // 4KB
    const int bid = blockIdx.x;
    const int mc = bid & 7;
    const int bh = bid >> 3;
    const int b = bh >> 3, h = bh & 7;
    const int tid = threadIdx.x;
    const int wave = tid >> 6, lane = tid & 63;
    const int wr = (wave >> 1) * 64, wc = (wave & 1) * 32;
    const int lm = lane & 15, lk = (lane >> 4) * 8;
    const unsigned short* Abase = phiQ + (size_t)bh * SEQ * FDIM + (size_t)mc * 128 * FDIM;
    const unsigned short* Bbase = kvT + (size_t)bh * HDIM * FDIM;

    f32x4_t acc[4][2];
#pragma unroll
    for (int i = 0; i < 4; i++)
#pragma unroll
        for (int j = 0; j < 2; j++)
            acc[i][j] = (f32x4_t){0.f, 0.f, 0.f, 0.f};

    for (int k0 = 0; k0 < FDIM; k0 += 32) {
#pragma unroll
        for (int it = 0; it < 2; ++it) {
            int t = tid + it * 256;
            const unsigned short* gp = Abase + (size_t)(t >> 2) * FDIM + k0 + (t & 3) * 8;
            __builtin_amdgcn_global_load_lds((gas_t)(const char*)gp,
                (las_t)((char*)As + t * 16), 16, 0, 0);
        }
        {
            int t = tid;
            const unsigned short* gp = Bbase + (size_t)(t >> 2) * FDIM + k0 + (t & 3) * 8;
            __builtin_amdgcn_global_load_lds((gas_t)(const char*)gp,
                (las_t)((char*)Bs + t * 16), 16, 0, 0);
        }
        __syncthreads();
        bf16x8_t af[4], bfr[2];
#pragma unroll
        for (int i = 0; i < 4; i++)
            af[i] = *(const bf16x8_t*)(As + (size_t)(wr + 16 * i + lm) * 32 + lk);
#pragma unroll
        for (int j = 0; j < 2; j++)
            bfr[j] = *(const bf16x8_t*)(Bs + (size_t)(wc + 16 * j + lm) * 32 + lk);
#pragma unroll
        for (int i = 0; i < 4; i++)
#pragma unroll
            for (int j = 0; j < 2; j++)
                acc[i][j] = __builtin_amdgcn_mfma_f32_16x16x32_bf16(af[i], bfr[j], acc[i][j], 0, 0, 0);
        __syncthreads();
    }

    const int col_l = lane & 15;
    const int quad4 = (lane >> 4) * 4;
#pragma unroll
    for (int i = 0; i < 4; i++) {
#pragma unroll
        for (int r = 0; r < 4; r++) {
            int s = mc * 128 + wr + 16 * i + quad4 + r;
            float zz = z[(size_t)bh * SEQ + s];
#pragma unroll
            for (int j = 0; j < 2; j++) {
                int d = wc + 16 * j + col_l;
                outX[(size_t)(b * SEQ + s) * DMODEL + h * HDIM + d] =
                    f2bu(acc[i][j][r] * zz);
            }
        }
    }
}

// ---------------------------------------------------------------- residual + LayerNorm
__global__ __launch_bounds__(512) void add_ln_kernel(
    const float* __restrict__ res, const float* __restrict__ tin,
    const float* __restrict__ g, const float* __restrict__ bb,
    float* __restrict__ out, unsigned short* __restrict__ out16)
{
    int row = blockIdx.x, t = threadIdx.x;
    size_t idx = (size_t)row * DMODEL + t;
    float val = tin[idx];
    if (res) val += res[idx];
    float s1 = val, s2 = val * val;
#pragma unroll
    for (int off = 32; off; off >>= 1) {
        s1 += __shfl_down(s1, off, 64);
        s2 += __shfl_down(s2, off, 64);
    }
    __shared__ float w1s[8], w2s[8];
    int wid = t >> 6, lane = t & 63;
    if (lane == 0) { w1s[wid] = s1; w2s[wid] = s2; }
    __syncthreads();
    if (t == 0) {
        float a1 = 0.f, a2 = 0.f;
#pragma unroll
        for (int i = 0; i < 8; i++) { a1 += w1s[i]; a2 += w2s[i]; }
        w1s[0] = a1 * (1.f / DMODEL);
        w2s[0] = a2 * (1.f / DMODEL);
    }
    __syncthreads();
    float m = w1s[0];
    float var = w2s[0] - m * m;
    float r = rsqrtf(var + 1e-5f);
    float y = (val - m) * r * g[t] + bb[t];
    out[idx] = y;
    if (out16) out16[idx] = f2bu(y);
}

// ---------------------------------------------------------------- pool + classify
__global__ __launch_bounds__(512) void pool_cls_kernel(
    const float* __restrict__ h, const float* __restrict__ cls_w,
    const float* __restrict__ cls_b, float* __restrict__ out)
{
    int b = blockIdx.x, t = threadIdx.x;
    float s = 0.f;
    for (int i = 0; i < SEQ; i++) s += h[((size_t)b * SEQ + i) * DMODEL + t];
    __shared__ float pooled[DMODEL];
    pooled[t] = s * (1.f / SEQ);
    __syncthreads();
    if (t < 16) {
        float acc = cls_b[t];
        for (int c = 0; c < DMODEL; c++) acc += pooled[c] * cls_w[c * 16 + t];
        out[b * 16 + t] = acc;
    }
}

// ----------------------------------------------------------------
extern "C" void kernel_launch(void* const* d_in, const int* in_sizes, int n_in,
                              void* d_out, int out_size, void* d_ws, size_t ws_size,
                              hipStream_t stream)
{
    const float* x      = (const float*)d_in[0];
    const float* pos    = (const float*)d_in[1];
    const float* enc_w1 = (const float*)d_in[2];
    const float* enc_b1 = (const float*)d_in[3];
    const float* enc_w2 = (const float*)d_in[4];
    const float* enc_b2 = (const float*)d_in[5];
    const float* enc_g  = (const float*)d_in[6];
    const float* enc_bb = (const float*)d_in[7];
    const float* wq = (const float*)d_in[8];
    const float* bq = (const float*)d_in[9];
    const float* wk = (const float*)d_in[10];
    const float* bk = (const float*)d_in[11];
    const float* wv = (const float*)d_in[12];
    const float* bv = (const float*)d_in[13];
    const float* wo = (const float*)d_in[14];
    const float* bo = (const float*)d_in[15];
    const float* ln1_g = (const float*)d_in[16];
    const float* ln1_b = (const float*)d_in[17];
    const float* w1 = (const float*)d_in[18];
    const float* b1 = (const float*)d_in[19];
    const float* w2 = (const float*)d_in[20];
    const float* b2 = (const float*)d_in[21];
    const float* ln2_g = (const float*)d_in[22];
    const float* ln2_b = (const float*)d_in[23];
    const float* omega = (const float*)d_in[24];
    const float* cls_w = (const float*)d_in[25];
    const float* cls_b = (const float*)d_in[26];
    float* out = (float*)d_out;

    const int N = NTOK;
    const int BH = BATCH * NHEAD;

    char* p = (char*)d_ws;
    float* hbuf = (float*)p;                   p += (size_t)N * DMODEL * 4;   // 32MB
    unsigned short* qb16 = (unsigned short*)p; p += (size_t)N * DMODEL * 2;   // 16MB
    unsigned short* kb16 = (unsigned short*)p; p += (size_t)N * DMODEL * 2;   // 16MB
    unsigned short* vT16 = (unsigned short*)p; p += (size_t)N * DMODEL * 2;   // 16MB
    unsigned short* h16  = (unsigned short*)p; p += (size_t)N * DMODEL * 2;   // 16MB
    unsigned short* mid16 = (unsigned short*)p; p += (size_t)N * 1024 * 2;    // 32MB
    unsigned short* attn16 = (unsigned short*)p; p += (size_t)N * DMODEL * 2; // 16MB
    unsigned short* phibuf = (unsigned short*)p; p += (size_t)BH * SEQ * FDIM * 2; // 67MB (phiT then phiQ)
    unsigned short* kvT  = (unsigned short*)p; p += (size_t)BH * HDIM * FDIM * 2;  // 4MB
    float* ksb = (float*)p;                    p += (size_t)BH * FDIM * 4;    // 128KB
    float* zb  = (float*)p;                    p += (size_t)BH * SEQ * 4;     // 512KB
    unsigned short* enc_w2t = (unsigned short*)p; p += (size_t)256 * 512 * 2;
    unsigned short* wqt = (unsigned short*)p;  p += (size_t)4 * 512 * 512 * 2;
    unsigned short* wkt = (unsigned short*)p;  p += (size_t)4 * 512 * 512 * 2;
    unsigned short* wvt = (unsigned short*)p;  p += (size_t)4 * 512 * 512 * 2;
    unsigned short* wot = (unsigned short*)p;  p += (size_t)4 * 512 * 512 * 2;
    unsigned short* w1t = (unsigned short*)p;  p += (size_t)4 * 512 * 1024 * 2;
    unsigned short* w2t = (unsigned short*)p;  p += (size_t)4 * 1024 * 512 * 2;
    unsigned short* omT = (unsigned short*)p;  p += (size_t)4 * 128 * 64 * 2;
    // t512 (f32, 32MB) aliases kb16+vT16 (both dead when Wo/FFN2 write it)
    float* t512 = (float*)kb16;

    // ---- weight conversion ----
    convT_kernel<<<dim3(16, 8), 256, 0, stream>>>(enc_w2, enc_w2t, 256, 512);
    for (int l = 0; l < 4; l++) {
        convT_kernel<<<dim3(16, 16), 256, 0, stream>>>(wq + (size_t)l * 262144, wqt + (size_t)l * 262144, 512, 512);
        convT_kernel<<<dim3(16, 16), 256, 0, stream>>>(wk + (size_t)l * 262144, wkt + (size_t)l * 262144, 512, 512);
        convT_kernel<<<dim3(16, 16), 256, 0, stream>>>(wv + (size_t)l * 262144, wvt + (size_t)l * 262144, 512, 512);
        convT_kernel<<<dim3(16, 16), 256, 0, stream>>>(wo + (size_t)l * 262144, wot + (size_t)l * 262144, 512, 512);
        convT_kernel<<<dim3(32, 16), 256, 0, stream>>>(w1 + (size_t)l * 524288, w1t + (size_t)l * 524288, 512, 1024);
        convT_kernel<<<dim3(16, 32), 256, 0, stream>>>(w2 + (size_t)l * 524288, w2t + (size_t)l * 524288, 1024, 512);
    }
    omT_kernel<<<128, 256, 0, stream>>>(omega, omT);

    // ---- encoder ----
    enc1_kernel<<<N, 256, 0, stream>>>(x, pos, enc_w1, enc_b1, mid16);
    gemm_bf16_kernel<0, 0><<<dim3(4, 128), 256, 0, stream>>>(mid16, enc_w2t, enc_b2, t512, N, 256, 512);
    add_ln_kernel<<<N, 512, 0, stream>>>(nullptr, t512, enc_g, enc_bb, hbuf, h16);

    // ---- layers ----
    for (int l = 0; l < 4; l++) {
        const unsigned short* omT_l = omT + (size_t)l * 8192;
        gemm_bf16_kernel<1, 0><<<dim3(4, 128), 256, 0, stream>>>(h16, wqt + (size_t)l * 262144, bq + l * DMODEL, qb16, N, 512, 512);
        gemm_bf16_kernel<1, 0><<<dim3(4, 128), 256, 0, stream>>>(h16, wkt + (size_t)l * 262144, bk + l * DMODEL, kb16, N, 512, 512);
        gemm_bf16_kernel<2, 0><<<dim3(4, 128), 256, 0, stream>>>(h16, wvt + (size_t)l * 262144, bv + l * DMODEL, vT16, N, 512, 512);
        zero_kernel<<<BH * FDIM / 256, 256, 0, stream>>>(ksb, BH * FDIM);
        feat_kernel<1><<<BATCH * NHEAD * 16, 256, 0, stream>>>(kb16, omT_l, phibuf, ksb, nullptr);
        kv_kernel<<<BH, 256, 0, stream>>>(phibuf, vT16, kvT);
        feat_kernel<0><<<BATCH * NHEAD * 16, 256, 0, stream>>>(qb16, omT_l, phibuf, ksb, zb);
        attn_kernel<<<BH * 8, 256, 0, stream>>>(phibuf, kvT, zb, attn16);
        gemm_bf16_kernel<0, 0><<<dim3(4, 128), 256, 0, stream>>>(attn16, wot + (size_t)l * 262144, bo + l * DMODEL, t512, N, 512, 512);
        add_ln_kernel<<<N, 512, 0, stream>>>(hbuf, t512, ln1_g + l * DMODEL, ln1_b + l * DMODEL, hbuf, h16);
        gemm_bf16_kernel<1, 1><<<dim3(8, 128), 256, 0, stream>>>(h16, w1t + (size_t)l * 524288, b1 + l * 1024, mid16, N, 512, 1024);
        gemm_bf16_kernel<0, 0><<<dim3(4, 128), 256, 0, stream>>>(mid16, w2t + (size_t)l * 524288, b2 + l * DMODEL, t512, N, 1024, 512);
        add_ln_kernel<<<N, 512, 0, stream>>>(hbuf, t512, ln2_g + l * DMODEL, ln2_b + l * DMODEL, hbuf, h16);
    }

    // ---- pool + classify ----
    pool_cls_kernel<<<BATCH, 512, 0, stream>>>(hbuf, cls_w, cls_b, out);
}

// Round 4
// 1384.897 us; speedup vs baseline: 6.1210x; 1.1361x over previous
//
#include <hip/hip_runtime.h>
#include <hip/hip_bf16.h>
#include <math.h>

// Dims (fixed): B=16, S=1024, N=16384, DM=512, H=8, D=64, F=256, L=4
#define NTOK 16384
#define BATCH 16
#define SEQ 1024
#define DMODEL 512
#define NHEAD 8
#define HDIM 64
#define FDIM 256
#define SCALE_QK 0.3535533905932738f   // 64^-0.25
#define SCALE2 0.125f                  // SCALE_QK^2
#define FSCALE 0.0625f                 // 256^-0.5

typedef __bf16 bf16x8_t __attribute__((ext_vector_type(8)));
typedef float f32x4_t  __attribute__((ext_vector_type(4)));
typedef unsigned short u16x8 __attribute__((ext_vector_type(8)));
typedef unsigned short u16x4 __attribute__((ext_vector_type(4)));
typedef const __attribute__((address_space(1))) char* gas_t;
typedef __attribute__((address_space(3))) char* las_t;

__device__ __forceinline__ float b2f(unsigned short u) {
    union { unsigned int i; float f; } c; c.i = ((unsigned int)u) << 16; return c.f;
}
__device__ __forceinline__ unsigned short f2bu(float f) {
    __hip_bfloat16 h = __float2bfloat16(f);
    return *(unsigned short*)&h;
}

// ---------------------------------------------------------------- zero
__global__ void zero_kernel(float* __restrict__ p, int n) {
    int i = blockIdx.x * 256 + threadIdx.x;
    if (i < n) p[i] = 0.f;
}

// ---------------------------------------------------------------- batched weight convert+transpose: W[K,N] f32 -> Wt[N,K] bf16, grid.z = layer
__global__ __launch_bounds__(256) void convT_batch_kernel(
    const float* __restrict__ W, unsigned short* __restrict__ Wt, int K, int N,
    size_t in_lstride, size_t out_lstride)
{
    int l = blockIdx.z;
    W  += (size_t)l * in_lstride;
    Wt += (size_t)l * out_lstride;
    __shared__ float tile[32][33];
    int k0 = blockIdx.y * 32, n0 = blockIdx.x * 32;
    int t = threadIdx.x;
    int r = t >> 3, c4 = (t & 7) * 4;
    float4 v = *(const float4*)(W + (size_t)(k0 + r) * N + n0 + c4);
    tile[r][c4 + 0] = v.x; tile[r][c4 + 1] = v.y;
    tile[r][c4 + 2] = v.z; tile[r][c4 + 3] = v.w;
    __syncthreads();
    ushort4 o;
    o.x = f2bu(tile[c4 + 0][r]); o.y = f2bu(tile[c4 + 1][r]);
    o.z = f2bu(tile[c4 + 2][r]); o.w = f2bu(tile[c4 + 3][r]);
    *(ushort4*)(Wt + (size_t)(n0 + r) * K + k0 + c4) = o;
}

// ---------------------------------------------------------------- omega transpose+scale
__global__ __launch_bounds__(256) void omT_kernel(
    const float* __restrict__ om, unsigned short* __restrict__ omT)
{
    int i = blockIdx.x * 256 + threadIdx.x;   // over 4*8192
    int l = i >> 13, rem = i & 8191;
    int f = rem >> 6, d = rem & 63;
    omT[(size_t)l * 8192 + f * 64 + d] = f2bu(om[(size_t)l * 8192 + d * 128 + f] * SCALE_QK);
}

// ---------------------------------------------------------------- encoder stage 1
__global__ __launch_bounds__(256) void enc1_kernel(
    const float* __restrict__ x, const float* __restrict__ pos,
    const float* __restrict__ w1, const float* __restrict__ b1,
    unsigned short* __restrict__ mid)
{
    int row = blockIdx.x, t = threadIdx.x;
    __shared__ float in6[6];
    if (t < 3) in6[t] = x[row * 3 + t];
    else if (t < 6) in6[t] = pos[row * 3 + (t - 3)];
    __syncthreads();
    float acc = b1[t];
#pragma unroll
    for (int j = 0; j < 6; j++) acc += in6[j] * w1[j * 256 + t];
    mid[(size_t)row * 256 + t] = f2bu(fmaxf(acc, 0.f));
}

// ---------------------------------------------------------------- bf16 MFMA GEMM: C = [relu](A[M,K] @ Bt[Nc,K]^T + bias)
// OUT_MODE: 0 = f32 rows, 1 = bf16 rows
template<int OUT_MODE, int RELU>
__global__ __launch_bounds__(256) void gemm_bf16_kernel(
    const unsigned short* __restrict__ A, const unsigned short* __restrict__ Bt,
    const float* __restrict__ bias, void* __restrict__ C,
    int M, int K, int Nc)
{
    __shared__ __align__(16) unsigned short As[128 * 32];
    __shared__ __align__(16) unsigned short Bs[128 * 32];
    const int tid = threadIdx.x;
    const int bm = blockIdx.y * 128, bn = blockIdx.x * 128;
    const int wave = tid >> 6, lane = tid & 63;
    const int wr = (wave >> 1) * 64, wc = (wave & 1) * 64;
    const int lm = lane & 15, lk = (lane >> 4) * 8;

    f32x4_t acc[4][4];
#pragma unroll
    for (int i = 0; i < 4; i++)
#pragma unroll
        for (int j = 0; j < 4; j++)
            acc[i][j] = (f32x4_t){0.f, 0.f, 0.f, 0.f};

    for (int k0 = 0; k0 < K; k0 += 32) {
#pragma unroll
        for (int it = 0; it < 2; ++it) {
            int t = tid + it * 256;
            const unsigned short* gp = A + (size_t)(bm + (t >> 2)) * K + k0 + (t & 3) * 8;
            __builtin_amdgcn_global_load_lds((gas_t)(const char*)gp,
                (las_t)((char*)As + t * 16), 16, 0, 0);
        }
#pragma unroll
        for (int it = 0; it < 2; ++it) {
            int t = tid + it * 256;
            const unsigned short* gp = Bt + (size_t)(bn + (t >> 2)) * K + k0 + (t & 3) * 8;
            __builtin_amdgcn_global_load_lds((gas_t)(const char*)gp,
                (las_t)((char*)Bs + t * 16), 16, 0, 0);
        }
        __syncthreads();
        bf16x8_t af[4], bfr[4];
#pragma unroll
        for (int i = 0; i < 4; i++)
            af[i] = *(const bf16x8_t*)(As + (size_t)(wr + 16 * i + lm) * 32 + lk);
#pragma unroll
        for (int j = 0; j < 4; j++)
            bfr[j] = *(const bf16x8_t*)(Bs + (size_t)(wc + 16 * j + lm) * 32 + lk);
#pragma unroll
        for (int i = 0; i < 4; i++)
#pragma unroll
            for (int j = 0; j < 4; j++)
                acc[i][j] = __builtin_amdgcn_mfma_f32_16x16x32_bf16(af[i], bfr[j], acc[i][j], 0, 0, 0);
        __syncthreads();
    }

    const int col_l = lane & 15;
    const int row_q = (lane >> 4) * 4;
#pragma unroll
    for (int i = 0; i < 4; i++) {
#pragma unroll
        for (int j = 0; j < 4; j++) {
            int gn = bn + wc + 16 * j + col_l;
            float bsv = bias[gn];
            int gm0 = bm + wr + 16 * i + row_q;
#pragma unroll
            for (int r = 0; r < 4; r++) {
                float v = acc[i][j][r] + bsv;
                if (RELU) v = fmaxf(v, 0.f);
                if (OUT_MODE == 1)
                    ((unsigned short*)C)[(size_t)(gm0 + r) * Nc + gn] = f2bu(v);
                else
                    ((float*)C)[(size_t)(gm0 + r) * Nc + gn] = v;
            }
        }
    }
}

// ---------------------------------------------------------------- fused QKV GEMM: A[M,512] @ WqkvT[1536,512]^T
// epilogue routes: cols [0,512) -> Q rows [N,512]; [512,1024) -> K rows; [1024,1536) -> vT [B,H,D,S]
__global__ __launch_bounds__(256) void gemm_qkv_kernel(
    const unsigned short* __restrict__ A, const unsigned short* __restrict__ Bt,
    const float* __restrict__ bq, const float* __restrict__ bk, const float* __restrict__ bv,
    unsigned short* __restrict__ Q, unsigned short* __restrict__ Kk,
    unsigned short* __restrict__ vT)
{
    __shared__ __align__(16) unsigned short As[128 * 32];
    __shared__ __align__(16) unsigned short Bs[128 * 32];
    const int tid = threadIdx.x;
    const int bm = blockIdx.y * 128, bn = blockIdx.x * 128;
    const int wave = tid >> 6, lane = tid & 63;
    const int wr = (wave >> 1) * 64, wc = (wave & 1) * 64;
    const int lm = lane & 15, lk = (lane >> 4) * 8;
    const int K = DMODEL;

    f32x4_t acc[4][4];
#pragma unroll
    for (int i = 0; i < 4; i++)
#pragma unroll
        for (int j = 0; j < 4; j++)
            acc[i][j] = (f32x4_t){0.f, 0.f, 0.f, 0.f};

    for (int k0 = 0; k0 < K; k0 += 32) {
#pragma unroll
        for (int it = 0; it < 2; ++it) {
            int t = tid + it * 256;
            const unsigned short* gp = A + (size_t)(bm + (t >> 2)) * K + k0 + (t & 3) * 8;
            __builtin_amdgcn_global_load_lds((gas_t)(const char*)gp,
                (las_t)((char*)As + t * 16), 16, 0, 0);
        }
#pragma unroll
        for (int it = 0; it < 2; ++it) {
            int t = tid + it * 256;
            const unsigned short* gp = Bt + (size_t)(bn + (t >> 2)) * K + k0 + (t & 3) * 8;
            __builtin_amdgcn_global_load_lds((gas_t)(const char*)gp,
                (las_t)((char*)Bs + t * 16), 16, 0, 0);
        }
        __syncthreads();
        bf16x8_t af[4], bfr[4];
#pragma unroll
        for (int i = 0; i < 4; i++)
            af[i] = *(const bf16x8_t*)(As + (size_t)(wr + 16 * i + lm) * 32 + lk);
#pragma unroll
        for (int j = 0; j < 4; j++)
            bfr[j] = *(const bf16x8_t*)(Bs + (size_t)(wc + 16 * j + lm) * 32 + lk);
#pragma unroll
        for (int i = 0; i < 4; i++)
#pragma unroll
            for (int j = 0; j < 4; j++)
                acc[i][j] = __builtin_amdgcn_mfma_f32_16x16x32_bf16(af[i], bfr[j], acc[i][j], 0, 0, 0);
        __syncthreads();
    }

    const int sect = bn >> 9;                  // uniform per block (128 | 512)
    const float* bias = (sect == 0) ? bq : (sect == 1) ? bk : bv;
    unsigned short* rowout = (sect == 0) ? Q : Kk;
    const int cb = bn & 511;
    const int col_l = lane & 15;
    const int row_q = (lane >> 4) * 4;
#pragma unroll
    for (int i = 0; i < 4; i++) {
#pragma unroll
        for (int j = 0; j < 4; j++) {
            int cn = cb + wc + 16 * j + col_l;         // 0..511 within section
            float bsv = bias[cn];
            int gm0 = bm + wr + 16 * i + row_q;
            if (sect < 2) {
#pragma unroll
                for (int r = 0; r < 4; r++)
                    rowout[(size_t)(gm0 + r) * DMODEL + cn] = f2bu(acc[i][j][r] + bsv);
            } else {
                // vT[b,h,d,s]; gm0 multiple of 4 within a 1024-row batch block
                int bb_ = gm0 >> 10, ss = gm0 & 1023;
                int hh_ = cn >> 6, dd = cn & 63;
                u16x4 o4;
#pragma unroll
                for (int r = 0; r < 4; r++) o4[r] = f2bu(acc[i][j][r] + bsv);
                *(u16x4*)(vT + (((size_t)(bb_ * NHEAD + hh_) * HDIM + dd) * SEQ + ss)) = o4;
            }
        }
    }
}

// ---------------------------------------------------------------- FAVOR feature kernel (MFMA)
// IS_K=1: write phiT [B,H,F,S] + atomicAdd ksum[B,H,F]
// IS_K=0: write phiQ [B,H,S,F] + z[B,H,S] = 1/(phi . ksum + eps)
template<int IS_K>
__global__ __launch_bounds__(256) void feat_kernel(
    const unsigned short* __restrict__ X,    // [N, DM] bf16
    const unsigned short* __restrict__ omT,  // [128][64] bf16 (pre-scaled)
    unsigned short* __restrict__ phi_out,
    float* __restrict__ ksum,
    float* __restrict__ z)
{
    const int bid = blockIdx.x;
    const int sc = bid & 15;
    const int h = (bid >> 4) & 7;
    const int b = bid >> 7;
    const int s0 = sc * 64;
    const int tid = threadIdx.x;

    __shared__ __align__(16) unsigned short xs[64 * 72];
    __shared__ __align__(16) unsigned short omTs[128 * 72];
    __shared__ __align__(16) unsigned short phis[64 * 264];
    __shared__ float hs[64];
    __shared__ float kss[256];

#pragma unroll
    for (int it = 0; it < 2; ++it) {
        int idx = tid + it * 256;
        int r = idx >> 3, c = (idx & 7) * 8;
        u16x8 v = *(const u16x8*)(X + (size_t)(b * SEQ + s0 + r) * DMODEL + h * HDIM + c);
        *(u16x8*)&xs[r * 72 + c] = v;
    }
#pragma unroll
    for (int it = 0; it < 4; ++it) {
        int idx = tid + it * 256;
        int r = idx >> 3, c = (idx & 7) * 8;
        u16x8 v = *(const u16x8*)(omT + (size_t)r * 64 + c);
        *(u16x8*)&omTs[r * 72 + c] = v;
    }
    if (!IS_K) kss[tid] = ksum[(size_t)(b * NHEAD + h) * FDIM + tid];
    __syncthreads();

    {
        int token = tid >> 2, seg = (tid & 3) * 16;
        float p = 0.f;
#pragma unroll
        for (int j = 0; j < 16; j++) {
            float xv = b2f(xs[token * 72 + seg + j]);
            p += xv * xv;
        }
        p += __shfl_down(p, 2, 4);
        p += __shfl_down(p, 1, 4);
        if ((tid & 3) == 0) hs[token] = 0.5f * SCALE2 * p;
    }

    const int wave = tid >> 6, lane = tid & 63;
    const int m0 = wave * 16;
    const int lm = lane & 15, lk = (lane >> 4) * 8;
    f32x4_t acc[8];
#pragma unroll
    for (int j = 0; j < 8; j++) acc[j] = (f32x4_t){0.f, 0.f, 0.f, 0.f};
#pragma unroll
    for (int ks = 0; ks < 2; ks++) {
        bf16x8_t af = *(const bf16x8_t*)&xs[(m0 + lm) * 72 + ks * 32 + lk];
#pragma unroll
        for (int j = 0; j < 8; j++) {
            bf16x8_t bfr = *(const bf16x8_t*)&omTs[(j * 16 + lm) * 72 + ks * 32 + lk];
            acc[j] = __builtin_amdgcn_mfma_f32_16x16x32_bf16(af, bfr, acc[j], 0, 0, 0);
        }
    }
    __syncthreads();

    const int col_l = lane & 15;
    const int quad4 = (lane >> 4) * 4;
#pragma unroll
    for (int j = 0; j < 8; j++) {
        int f = j * 16 + col_l;
#pragma unroll
        for (int r = 0; r < 4; r++) {
            int m = m0 + quad4 + r;
            float u = acc[j][r];
            float hh = hs[m];
            phis[m * 264 + f]       = f2bu(__expf(u - hh) * FSCALE);
            phis[m * 264 + 128 + f] = f2bu(__expf(-u - hh) * FSCALE);
        }
    }
    __syncthreads();

    if (IS_K) {
        int f = tid;
        size_t base = ((size_t)(b * NHEAD + h) * FDIM + f) * SEQ + s0;
        float kp = 0.f;
#pragma unroll
        for (int mm = 0; mm < 64; mm += 8) {
            u16x8 v8;
#pragma unroll
            for (int jj = 0; jj < 8; jj++) {
                unsigned short pv = phis[(mm + jj) * 264 + f];
                v8[jj] = pv;
                kp += b2f(pv);
            }
            *(u16x8*)(phi_out + base + mm) = v8;
        }
        atomicAdd(&ksum[(size_t)(b * NHEAD + h) * FDIM + f], kp);
    } else {
        int m = tid >> 2, fp = (tid & 3) * 64;
        size_t base = ((size_t)(b * NHEAD + h) * SEQ + s0 + m) * FDIM + fp;
        float zp = 0.f;
#pragma unroll
        for (int jj = 0; jj < 64; jj += 8) {
            u16x8 v = *(const u16x8*)&phis[m * 264 + fp + jj];
            *(u16x8*)(phi_out + base + jj) = v;
#pragma unroll
            for (int e = 0; e < 8; e++) zp += b2f(v[e]) * kss[fp + jj + e];
        }
        zp += __shfl_down(zp, 2, 4);
        zp += __shfl_down(zp, 1, 4);
        if ((tid & 3) == 0)
            z[(size_t)(b * NHEAD + h) * SEQ + s0 + m] = 1.f / (zp + 1e-6f);
    }
}

// ---------------------------------------------------------------- kv GEMM: kvT[bh][d][f] = sum_s phiT[bh][f][s] * vT[bh][d][s]
__global__ __launch_bounds__(256) void kv_kernel(
    const unsigned short* __restrict__ phiT,
    const unsigned short* __restrict__ vT,
    unsigned short* __restrict__ kvT)
{
    __shared__ __align__(16) unsigned short As[256 * 32];
    __shared__ __align__(16) unsigned short Bs[64 * 32];
    const int bh = blockIdx.x;
    const int tid = threadIdx.x;
    const int wave = tid >> 6, lane = tid & 63;
    const int wr = wave * 64;
    const int lm = lane & 15, lk = (lane >> 4) * 8;
    const unsigned short* Abase = phiT + (size_t)bh * FDIM * SEQ;
    const unsigned short* Bbase = vT + (size_t)bh * HDIM * SEQ;

    f32x4_t acc[4][4];
#pragma unroll
    for (int i = 0; i < 4; i++)
#pragma unroll
        for (int j = 0; j < 4; j++)
            acc[i][j] = (f32x4_t){0.f, 0.f, 0.f, 0.f};

    for (int k0 = 0; k0 < SEQ; k0 += 32) {
#pragma unroll
        for (int it = 0; it < 4; ++it) {
            int t = tid + it * 256;
            const unsigned short* gp = Abase + (size_t)(t >> 2) * SEQ + k0 + (t & 3) * 8;
            __builtin_amdgcn_global_load_lds((gas_t)(const char*)gp,
                (las_t)((char*)As + t * 16), 16, 0, 0);
        }
        {
            int t = tid;
            const unsigned short* gp = Bbase + (size_t)(t >> 2) * SEQ + k0 + (t & 3) * 8;
            __builtin_amdgcn_global_load_lds((gas_t)(const char*)gp,
                (las_t)((char*)Bs + t * 16), 16, 0, 0);
        }
        __syncthreads();
        bf16x8_t af[4], bfr[4];
#pragma unroll
        for (int i = 0; i < 4; i++)
            af[i] = *(const bf16x8_t*)(As + (size_t)(wr + 16 * i + lm) * 32 + lk);
#pragma unroll
        for (int j = 0; j < 4; j++)
            bfr[j] = *(const bf16x8_t*)(Bs + (size_t)(16 * j + lm) * 32 + lk);
#pragma unroll
        for (int i = 0; i < 4; i++)
#pragma unroll
            for (int j = 0; j < 4; j++)
                acc[i][j] = __builtin_amdgcn_mfma_f32_16x16x32_bf16(af[i], bfr[j], acc[i][j], 0, 0, 0);
        __syncthreads();
    }

    const int col_l = lane & 15;
    const int quad4 = (lane >> 4) * 4;
#pragma unroll
    for (int i = 0; i < 4; i++) {
#pragma unroll
        for (int j = 0; j < 4; j++) {
            int f0 = wr + 16 * i + quad4;
            int d = 16 * j + col_l;
            u16x4 o4;
#pragma unroll
            for (int r = 0; r < 4; r++) o4[r] = f2bu(acc[i][j][r]);
            *(u16x4*)(kvT + (size_t)bh * HDIM * FDIM + (size_t)d * FDIM + f0) = o4;
        }
    }
}

// ---------------------------------------------------------------- attn GEMM: out[s, h*64+d] = z[s] * sum_f phiQ[s,f] * kvT[d,f]
__global__ __launch_bounds__(256) void attn_kernel(
    const unsigned short* __restrict__ phiQ,
    const unsigned short* __restrict__ kvT,
    const float* __restrict__ z,
    unsigned short* __restrict__ outX)
{
    __shared__ __align__(16) unsigned short As[128 * 32];
    __shared__ __align__(16) unsigned short Bs[64 * 32];
    const int bid = blockIdx.x;
    const int mc = bid & 7;
    const int bh = bid >> 3;
    const int b = bh >> 3, h = bh & 7;
    const int tid = threadIdx.x;
    const int wave = tid >> 6, lane = tid & 63;
    const int wr = (wave >> 1) * 64, wc = (wave & 1) * 32;
    const int lm = lane & 15, lk = (lane >> 4) * 8;
    const unsigned short* Abase = phiQ + (size_t)bh * SEQ * FDIM + (size_t)mc * 128 * FDIM;
    const unsigned short* Bbase = kvT + (size_t)bh * HDIM * FDIM;

    f32x4_t acc[4][2];
#pragma unroll
    for (int i = 0; i < 4; i++)
#pragma unroll
        for (int j = 0; j < 2; j++)
            acc[i][j] = (f32x4_t){0.f, 0.f, 0.f, 0.f};

    for (int k0 = 0; k0 < FDIM; k0 += 32) {
#pragma unroll
        for (int it = 0; it < 2; ++it) {
            int t = tid + it * 256;
            const unsigned short* gp = Abase + (size_t)(t >> 2) * FDIM + k0 + (t & 3) * 8;
            __builtin_amdgcn_global_load_lds((gas_t)(const char*)gp,
                (las_t)((char*)As + t * 16), 16, 0, 0);
        }
        {
            int t = tid;
            const unsigned short* gp = Bbase + (size_t)(t >> 2) * FDIM + k0 + (t & 3) * 8;
            __builtin_amdgcn_global_load_lds((gas_t)(const char*)gp,
                (las_t)((char*)Bs + t * 16), 16, 0, 0);
        }
        __syncthreads();
        bf16x8_t af[4], bfr[2];
#pragma unroll
        for (int i = 0; i < 4; i++)
            af[i] = *(const bf16x8_t*)(As + (size_t)(wr + 16 * i + lm) * 32 + lk);
#pragma unroll
        for (int j = 0; j < 2; j++)
            bfr[j] = *(const bf16x8_t*)(Bs + (size_t)(wc + 16 * j + lm) * 32 + lk);
#pragma unroll
        for (int i = 0; i < 4; i++)
#pragma unroll
            for (int j = 0; j < 2; j++)
                acc[i][j] = __builtin_amdgcn_mfma_f32_16x16x32_bf16(af[i], bfr[j], acc[i][j], 0, 0, 0);
        __syncthreads();
    }

    const int col_l = lane & 15;
    const int quad4 = (lane >> 4) * 4;
#pragma unroll
    for (int i = 0; i < 4; i++) {
#pragma unroll
        for (int r = 0; r < 4; r++) {
            int s = mc * 128 + wr + 16 * i + quad4 + r;
            float zz = z[(size_t)bh * SEQ + s];
#pragma unroll
            for (int j = 0; j < 2; j++) {
                int d = wc + 16 * j + col_l;
                outX[(size_t)(b * SEQ + s) * DMODEL + h * HDIM + d] =
                    f2bu(acc[i][j][r] * zz);
            }
        }
    }
}

// ---------------------------------------------------------------- residual(bf16) + GEMM-out(f32) + LayerNorm -> bf16
template<int HAS_RES>
__global__ __launch_bounds__(512) void add_ln_kernel(
    const unsigned short* __restrict__ res16, const float* __restrict__ tin,
    const float* __restrict__ g, const float* __restrict__ bb,
    unsigned short* __restrict__ out16)
{
    int row = blockIdx.x, t = threadIdx.x;
    size_t idx = (size_t)row * DMODEL + t;
    float val = tin[idx];
    if (HAS_RES) val += b2f(res16[idx]);
    float s1 = val, s2 = val * val;
#pragma unroll
    for (int off = 32; off; off >>= 1) {
        s1 += __shfl_down(s1, off, 64);
        s2 += __shfl_down(s2, off, 64);
    }
    __shared__ float w1s[8], w2s[8];
    int wid = t >> 6, lane = t & 63;
    if (lane == 0) { w1s[wid] = s1; w2s[wid] = s2; }
    __syncthreads();
    if (t == 0) {
        float a1 = 0.f, a2 = 0.f;
#pragma unroll
        for (int i = 0; i < 8; i++) { a1 += w1s[i]; a2 += w2s[i]; }
        w1s[0] = a1 * (1.f / DMODEL);
        w2s[0] = a2 * (1.f / DMODEL);
    }
    __syncthreads();
    float m = w1s[0];
    float var = w2s[0] - m * m;
    float r = rsqrtf(var + 1e-5f);
    out16[idx] = f2bu((val - m) * r * g[t] + bb[t]);
}

// ---------------------------------------------------------------- pool stage 1: partial sums over 64-token chunks
__global__ __launch_bounds__(256) void pool_part_kernel(
    const unsigned short* __restrict__ h16, float* __restrict__ pbuf)
{
    int blk = blockIdx.x;              // b*16 + chunk
    int b = blk >> 4, ch = blk & 15;
    int t = threadIdx.x;
    int d0 = t * 2;
    float a0 = 0.f, a1 = 0.f;
    const unsigned short* base = h16 + ((size_t)(b * SEQ + ch * 64) * DMODEL) + d0;
#pragma unroll 4
    for (int s = 0; s < 64; s++) {
        ushort2 v = *(const ushort2*)(base + (size_t)s * DMODEL);
        a0 += b2f(v.x); a1 += b2f(v.y);
    }
    float2 o = make_float2(a0, a1);
    *(float2*)(pbuf + (size_t)blk * DMODEL + d0) = o;
}

// ---------------------------------------------------------------- pool stage 2 + classify
__global__ __launch_bounds__(512) void cls_kernel(
    const float* __restrict__ pbuf, const float* __restrict__ cls_w,
    const float* __restrict__ cls_b, float* __restrict__ out)
{
    int b = blockIdx.x, t = threadIdx.x;
    float s = 0.f;
#pragma unroll
    for (int c = 0; c < 16; c++) s += pbuf[(size_t)(b * 16 + c) * DMODEL + t];
    __shared__ float pooled[DMODEL];
    pooled[t] = s * (1.f / SEQ);
    __syncthreads();
    if (t < 16) {
        float acc = cls_b[t];
        for (int c = 0; c < DMODEL; c++) acc += pooled[c] * cls_w[c * 16 + t];
        out[b * 16 + t] = acc;
    }
}

// ----------------------------------------------------------------
extern "C" void kernel_launch(void* const* d_in, const int* in_sizes, int n_in,
                              void* d_out, int out_size, void* d_ws, size_t ws_size,
                              hipStream_t stream)
{
    const float* x      = (const float*)d_in[0];
    const float* pos    = (const float*)d_in[1];
    const float* enc_w1 = (const float*)d_in[2];
    const float* enc_b1 = (const float*)d_in[3];
    const float* enc_w2 = (const float*)d_in[4];
    const float* enc_b2 = (const float*)d_in[5];
    const float* enc_g  = (const float*)d_in[6];
    const float* enc_bb = (const float*)d_in[7];
    const float* wq = (const float*)d_in[8];
    const float* bq = (const float*)d_in[9];
    const float* wk = (const float*)d_in[10];
    const float* bk = (const float*)d_in[11];
    const float* wv = (const float*)d_in[12];
    const float* bv = (const float*)d_in[13];
    const float* wo = (const float*)d_in[14];
    const float* bo = (const float*)d_in[15];
    const float* ln1_g = (const float*)d_in[16];
    const float* ln1_b = (const float*)d_in[17];
    const float* w1 = (const float*)d_in[18];
    const float* b1 = (const float*)d_in[19];
    const float* w2 = (const float*)d_in[20];
    const float* b2 = (const float*)d_in[21];
    const float* ln2_g = (const float*)d_in[22];
    const float* ln2_b = (const float*)d_in[23];
    const float* omega = (const float*)d_in[24];
    const float* cls_w = (const float*)d_in[25];
    const float* cls_b = (const float*)d_in[26];
    float* out = (float*)d_out;

    const int N = NTOK;
    const int BH = BATCH * NHEAD;

    char* p = (char*)d_ws;
    unsigned short* qb16 = (unsigned short*)p; p += (size_t)N * DMODEL * 2;   // 16MB
    unsigned short* kb16 = (unsigned short*)p; p += (size_t)N * DMODEL * 2;   // 16MB
    unsigned short* vT16 = (unsigned short*)p; p += (size_t)N * DMODEL * 2;   // 16MB
    unsigned short* h16  = (unsigned short*)p; p += (size_t)N * DMODEL * 2;   // 16MB
    unsigned short* mid16 = (unsigned short*)p; p += (size_t)N * 1024 * 2;    // 32MB
    unsigned short* attn16 = (unsigned short*)p; p += (size_t)N * DMODEL * 2; // 16MB
    unsigned short* phibuf = (unsigned short*)p; p += (size_t)BH * SEQ * FDIM * 2; // 67MB
    unsigned short* kvT  = (unsigned short*)p; p += (size_t)BH * HDIM * FDIM * 2;  // 4MB
    float* ksb = (float*)p;                    p += (size_t)BH * FDIM * 4;    // 128KB
    float* zb  = (float*)p;                    p += (size_t)BH * SEQ * 4;     // 512KB
    float* pbuf = (float*)p;                   p += (size_t)BATCH * 16 * DMODEL * 4; // 512KB
    unsigned short* enc_w2t = (unsigned short*)p; p += (size_t)256 * 512 * 2;
    unsigned short* wqkvt = (unsigned short*)p; p += (size_t)4 * 1536 * 512 * 2;  // 6MB
    unsigned short* wot = (unsigned short*)p;  p += (size_t)4 * 512 * 512 * 2;
    unsigned short* w1t = (unsigned short*)p;  p += (size_t)4 * 512 * 1024 * 2;
    unsigned short* w2t = (unsigned short*)p;  p += (size_t)4 * 1024 * 512 * 2;
    unsigned short* omT = (unsigned short*)p;  p += (size_t)4 * 128 * 64 * 2;
    // t512 (f32, 32MB) aliases kb16+vT16 (both dead when Wo/FFN2 write it)
    float* t512 = (float*)kb16;

    // ---- weight conversion (batched over layers) ----
    convT_batch_kernel<<<dim3(16, 8, 1), 256, 0, stream>>>(enc_w2, enc_w2t, 256, 512, 0, 0);
    convT_batch_kernel<<<dim3(16, 16, 4), 256, 0, stream>>>(wq, wqkvt,            512, 512, 262144, 786432);
    convT_batch_kernel<<<dim3(16, 16, 4), 256, 0, stream>>>(wk, wqkvt + 262144,   512, 512, 262144, 786432);
    convT_batch_kernel<<<dim3(16, 16, 4), 256, 0, stream>>>(wv, wqkvt + 524288,   512, 512, 262144, 786432);
    convT_batch_kernel<<<dim3(16, 16, 4), 256, 0, stream>>>(wo, wot, 512, 512, 262144, 262144);
    convT_batch_kernel<<<dim3(32, 16, 4), 256, 0, stream>>>(w1, w1t, 512, 1024, 524288, 524288);
    convT_batch_kernel<<<dim3(16, 32, 4), 256, 0, stream>>>(w2, w2t, 1024, 512, 524288, 524288);
    omT_kernel<<<128, 256, 0, stream>>>(omega, omT);

    // ---- encoder ----
    enc1_kernel<<<N, 256, 0, stream>>>(x, pos, enc_w1, enc_b1, mid16);
    gemm_bf16_kernel<0, 0><<<dim3(4, 128), 256, 0, stream>>>(mid16, enc_w2t, enc_b2, t512, N, 256, 512);
    add_ln_kernel<0><<<N, 512, 0, stream>>>(nullptr, t512, enc_g, enc_bb, h16);

    // ---- layers ----
    for (int l = 0; l < 4; l++) {
        const unsigned short* omT_l = omT + (size_t)l * 8192;
        gemm_qkv_kernel<<<dim3(12, 128), 256, 0, stream>>>(
            h16, wqkvt + (size_t)l * 786432,
            bq + l * DMODEL, bk + l * DMODEL, bv + l * DMODEL,
            qb16, kb16, vT16);
        zero_kernel<<<BH * FDIM / 256, 256, 0, stream>>>(ksb, BH * FDIM);
        feat_kernel<1><<<BATCH * NHEAD * 16, 256, 0, stream>>>(kb16, omT_l, phibuf, ksb, nullptr);
        kv_kernel<<<BH, 256, 0, stream>>>(phibuf, vT16, kvT);
        feat_kernel<0><<<BATCH * NHEAD * 16, 256, 0, stream>>>(qb16, omT_l, phibuf, ksb, zb);
        attn_kernel<<<BH * 8, 256, 0, stream>>>(phibuf, kvT, zb, attn16);
        gemm_bf16_kernel<0, 0><<<dim3(4, 128), 256, 0, stream>>>(attn16, wot + (size_t)l * 262144, bo + l * DMODEL, t512, N, 512, 512);
        add_ln_kernel<1><<<N, 512, 0, stream>>>(h16, t512, ln1_g + l * DMODEL, ln1_b + l * DMODEL, h16);
        gemm_bf16_kernel<1, 1><<<dim3(8, 128), 256, 0, stream>>>(h16, w1t + (size_t)l * 524288, b1 + l * 1024, mid16, N, 512, 1024);
        gemm_bf16_kernel<0, 0><<<dim3(4, 128), 256, 0, stream>>>(mid16, w2t + (size_t)l * 524288, b2 + l * DMODEL, t512, N, 1024, 512);
        add_ln_kernel<1><<<N, 512, 0, stream>>>(h16, t512, ln2_g + l * DMODEL, ln2_b + l * DMODEL, h16);
    }

    // ---- pool + classify ----
    pool_part_kernel<<<BATCH * 16, 256, 0, stream>>>(h16, pbuf);
    cls_kernel<<<BATCH, 512, 0, stream>>>(pbuf, cls_w, cls_b, out);
}

// Round 5
// 1258.365 us; speedup vs baseline: 6.7365x; 1.1006x over previous
//
#include <hip/hip_runtime.h>
#include <hip/hip_bf16.h>
#include <math.h>

// Dims (fixed): B=16, S=1024, N=16384, DM=512, H=8, D=64, F=256, L=4
#define NTOK 16384
#define BATCH 16
#define SEQ 1024
#define DMODEL 512
#define NHEAD 8
#define HDIM 64
#define FDIM 256
#define BH_TOT 128
#define SCALE_QK 0.3535533905932738f   // 64^-0.25
#define SCALE2 0.125f                  // SCALE_QK^2
#define FSCALE 0.0625f                 // 256^-0.5

typedef __bf16 bf16x8_t __attribute__((ext_vector_type(8)));
typedef __bf16 bf16x4_t __attribute__((ext_vector_type(4)));
typedef float f32x4_t  __attribute__((ext_vector_type(4)));
typedef unsigned short u16x8 __attribute__((ext_vector_type(8)));
typedef unsigned short u16x4 __attribute__((ext_vector_type(4)));
typedef const __attribute__((address_space(1))) char* gas_t;
typedef __attribute__((address_space(3))) char* las_t;

__device__ __forceinline__ float b2f(unsigned short u) {
    union { unsigned int i; float f; } c; c.i = ((unsigned int)u) << 16; return c.f;
}
__device__ __forceinline__ unsigned short f2bu(float f) {
    __hip_bfloat16 h = __float2bfloat16(f);
    return *(unsigned short*)&h;
}

// ---------------------------------------------------------------- zero
__global__ void zero_kernel(float* __restrict__ p, int n) {
    int i = blockIdx.x * 256 + threadIdx.x;
    if (i < n) p[i] = 0.f;
}

// ---------------------------------------------------------------- batched weight convert+transpose: W[K,N] f32 -> Wt[N,K] bf16, grid.z = layer
__global__ __launch_bounds__(256) void convT_batch_kernel(
    const float* __restrict__ W, unsigned short* __restrict__ Wt, int K, int N,
    size_t in_lstride, size_t out_lstride)
{
    int l = blockIdx.z;
    W  += (size_t)l * in_lstride;
    Wt += (size_t)l * out_lstride;
    __shared__ float tile[32][33];
    int k0 = blockIdx.y * 32, n0 = blockIdx.x * 32;
    int t = threadIdx.x;
    int r = t >> 3, c4 = (t & 7) * 4;
    float4 v = *(const float4*)(W + (size_t)(k0 + r) * N + n0 + c4);
    tile[r][c4 + 0] = v.x; tile[r][c4 + 1] = v.y;
    tile[r][c4 + 2] = v.z; tile[r][c4 + 3] = v.w;
    __syncthreads();
    ushort4 o;
    o.x = f2bu(tile[c4 + 0][r]); o.y = f2bu(tile[c4 + 1][r]);
    o.z = f2bu(tile[c4 + 2][r]); o.w = f2bu(tile[c4 + 3][r]);
    *(ushort4*)(Wt + (size_t)(n0 + r) * K + k0 + c4) = o;
}

// ---------------------------------------------------------------- omega transpose+scale
__global__ __launch_bounds__(256) void omT_kernel(
    const float* __restrict__ om, unsigned short* __restrict__ omT)
{
    int i = blockIdx.x * 256 + threadIdx.x;   // over 4*8192
    int l = i >> 13, rem = i & 8191;
    int f = rem >> 6, d = rem & 63;
    omT[(size_t)l * 8192 + f * 64 + d] = f2bu(om[(size_t)l * 8192 + d * 128 + f] * SCALE_QK);
}

// ---------------------------------------------------------------- encoder stage 1
__global__ __launch_bounds__(256) void enc1_kernel(
    const float* __restrict__ x, const float* __restrict__ pos,
    const float* __restrict__ w1, const float* __restrict__ b1,
    unsigned short* __restrict__ mid)
{
    int row = blockIdx.x, t = threadIdx.x;
    __shared__ float in6[6];
    if (t < 3) in6[t] = x[row * 3 + t];
    else if (t < 6) in6[t] = pos[row * 3 + (t - 3)];
    __syncthreads();
    float acc = b1[t];
#pragma unroll
    for (int j = 0; j < 6; j++) acc += in6[j] * w1[j * 256 + t];
    mid[(size_t)row * 256 + t] = f2bu(fmaxf(acc, 0.f));
}

// ---------------------------------------------------------------- bf16 MFMA GEMM: C = [relu](A[M,K] @ Bt[Nc,K]^T + bias) -> bf16
template<int RELU>
__global__ __launch_bounds__(256) void gemm_bf16_kernel(
    const unsigned short* __restrict__ A, const unsigned short* __restrict__ Bt,
    const float* __restrict__ bias, unsigned short* __restrict__ C,
    int M, int K, int Nc)
{
    __shared__ __align__(16) unsigned short As[128 * 32];
    __shared__ __align__(16) unsigned short Bs[128 * 32];
    const int tid = threadIdx.x;
    const int bm = blockIdx.y * 128, bn = blockIdx.x * 128;
    const int wave = tid >> 6, lane = tid & 63;
    const int wr = (wave >> 1) * 64, wc = (wave & 1) * 64;
    const int lm = lane & 15, lk = (lane >> 4) * 8;

    f32x4_t acc[4][4];
#pragma unroll
    for (int i = 0; i < 4; i++)
#pragma unroll
        for (int j = 0; j < 4; j++)
            acc[i][j] = (f32x4_t){0.f, 0.f, 0.f, 0.f};

    for (int k0 = 0; k0 < K; k0 += 32) {
#pragma unroll
        for (int it = 0; it < 2; ++it) {
            int t = tid + it * 256;
            const unsigned short* gp = A + (size_t)(bm + (t >> 2)) * K + k0 + (t & 3) * 8;
            __builtin_amdgcn_global_load_lds((gas_t)(const char*)gp,
                (las_t)((char*)As + t * 16), 16, 0, 0);
        }
#pragma unroll
        for (int it = 0; it < 2; ++it) {
            int t = tid + it * 256;
            const unsigned short* gp = Bt + (size_t)(bn + (t >> 2)) * K + k0 + (t & 3) * 8;
            __builtin_amdgcn_global_load_lds((gas_t)(const char*)gp,
                (las_t)((char*)Bs + t * 16), 16, 0, 0);
        }
        __syncthreads();
        bf16x8_t af[4], bfr[4];
#pragma unroll
        for (int i = 0; i < 4; i++)
            af[i] = *(const bf16x8_t*)(As + (size_t)(wr + 16 * i + lm) * 32 + lk);
#pragma unroll
        for (int j = 0; j < 4; j++)
            bfr[j] = *(const bf16x8_t*)(Bs + (size_t)(wc + 16 * j + lm) * 32 + lk);
#pragma unroll
        for (int i = 0; i < 4; i++)
#pragma unroll
            for (int j = 0; j < 4; j++)
                acc[i][j] = __builtin_amdgcn_mfma_f32_16x16x32_bf16(af[i], bfr[j], acc[i][j], 0, 0, 0);
        __syncthreads();
    }

    const int col_l = lane & 15;
    const int row_q = (lane >> 4) * 4;
#pragma unroll
    for (int i = 0; i < 4; i++) {
#pragma unroll
        for (int j = 0; j < 4; j++) {
            int gn = bn + wc + 16 * j + col_l;
            float bsv = bias[gn];
            int gm0 = bm + wr + 16 * i + row_q;
#pragma unroll
            for (int r = 0; r < 4; r++) {
                float v = acc[i][j][r] + bsv;
                if (RELU) v = fmaxf(v, 0.f);
                C[(size_t)(gm0 + r) * Nc + gn] = f2bu(v);
            }
        }
    }
}

// ---------------------------------------------------------------- fused QKV GEMM: A[M,512] @ WqkvT[1536,512]^T
__global__ __launch_bounds__(256) void gemm_qkv_kernel(
    const unsigned short* __restrict__ A, const unsigned short* __restrict__ Bt,
    const float* __restrict__ bq, const float* __restrict__ bk, const float* __restrict__ bv,
    unsigned short* __restrict__ Q, unsigned short* __restrict__ Kk,
    unsigned short* __restrict__ vT)
{
    __shared__ __align__(16) unsigned short As[128 * 32];
    __shared__ __align__(16) unsigned short Bs[128 * 32];
    const int tid = threadIdx.x;
    const int bm = blockIdx.y * 128, bn = blockIdx.x * 128;
    const int wave = tid >> 6, lane = tid & 63;
    const int wr = (wave >> 1) * 64, wc = (wave & 1) * 64;
    const int lm = lane & 15, lk = (lane >> 4) * 8;
    const int K = DMODEL;

    f32x4_t acc[4][4];
#pragma unroll
    for (int i = 0; i < 4; i++)
#pragma unroll
        for (int j = 0; j < 4; j++)
            acc[i][j] = (f32x4_t){0.f, 0.f, 0.f, 0.f};

    for (int k0 = 0; k0 < K; k0 += 32) {
#pragma unroll
        for (int it = 0; it < 2; ++it) {
            int t = tid + it * 256;
            const unsigned short* gp = A + (size_t)(bm + (t >> 2)) * K + k0 + (t & 3) * 8;
            __builtin_amdgcn_global_load_lds((gas_t)(const char*)gp,
                (las_t)((char*)As + t * 16), 16, 0, 0);
        }
#pragma unroll
        for (int it = 0; it < 2; ++it) {
            int t = tid + it * 256;
            const unsigned short* gp = Bt + (size_t)(bn + (t >> 2)) * K + k0 + (t & 3) * 8;
            __builtin_amdgcn_global_load_lds((gas_t)(const char*)gp,
                (las_t)((char*)Bs + t * 16), 16, 0, 0);
        }
        __syncthreads();
        bf16x8_t af[4], bfr[4];
#pragma unroll
        for (int i = 0; i < 4; i++)
            af[i] = *(const bf16x8_t*)(As + (size_t)(wr + 16 * i + lm) * 32 + lk);
#pragma unroll
        for (int j = 0; j < 4; j++)
            bfr[j] = *(const bf16x8_t*)(Bs + (size_t)(wc + 16 * j + lm) * 32 + lk);
#pragma unroll
        for (int i = 0; i < 4; i++)
#pragma unroll
            for (int j = 0; j < 4; j++)
                acc[i][j] = __builtin_amdgcn_mfma_f32_16x16x32_bf16(af[i], bfr[j], acc[i][j], 0, 0, 0);
        __syncthreads();
    }

    const int sect = bn >> 9;
    const float* bias = (sect == 0) ? bq : (sect == 1) ? bk : bv;
    unsigned short* rowout = (sect == 0) ? Q : Kk;
    const int cb = bn & 511;
    const int col_l = lane & 15;
    const int row_q = (lane >> 4) * 4;
#pragma unroll
    for (int i = 0; i < 4; i++) {
#pragma unroll
        for (int j = 0; j < 4; j++) {
            int cn = cb + wc + 16 * j + col_l;
            float bsv = bias[cn];
            int gm0 = bm + wr + 16 * i + row_q;
            if (sect < 2) {
#pragma unroll
                for (int r = 0; r < 4; r++)
                    rowout[(size_t)(gm0 + r) * DMODEL + cn] = f2bu(acc[i][j][r] + bsv);
            } else {
                int bb_ = gm0 >> 10, ss = gm0 & 1023;
                int hh_ = cn >> 6, dd = cn & 63;
                u16x4 o4;
#pragma unroll
                for (int r = 0; r < 4; r++) o4[r] = f2bu(acc[i][j][r] + bsv);
                *(u16x4*)(vT + (((size_t)(bb_ * NHEAD + hh_) * HDIM + dd) * SEQ + ss)) = o4;
            }
        }
    }
}

// ---------------------------------------------------------------- fused FAVOR K-features + kv accumulate
// grid = BH*4 (256-token chunks); per block: 4 subtiles of 64 tokens.
// phiK computed via MFMA, stored transposed [f][s] in LDS, MFMA'd against vT.
// out: kvpart[chunk][bh][d][f] f32, ksum[bh][f] (atomicAdd)
__global__ __launch_bounds__(256) void favor_k_kv_kernel(
    const unsigned short* __restrict__ Kx,   // [N,DM] bf16
    const unsigned short* __restrict__ vT,   // [BH,64,1024] bf16
    const unsigned short* __restrict__ omT,  // [128][64] bf16 pre-scaled
    float* __restrict__ kvpart,
    float* __restrict__ ksum)
{
    const int bid = blockIdx.x;
    const int chunk = bid & 3;
    const int bh = bid >> 2;
    const int b = bh >> 3, h = bh & 7;
    const int tid = threadIdx.x;
    const int wave = tid >> 6, lane = tid & 63;
    const int lm = lane & 15, lk = (lane >> 4) * 8;
    const int col_l = lane & 15, quad4 = (lane >> 4) * 4;
    const int wr = wave * 64;       // f-rows for kv MFMA
    const int m0 = wave * 16;       // tokens for u MFMA

    __shared__ __align__(16) unsigned short xs[64 * 72];     // 9KB
    __shared__ __align__(16) unsigned short phiT[256 * 72];  // 36KB [f][s] stride 72
    __shared__ float hs[64];

    f32x4_t acc_kv[4][4];
#pragma unroll
    for (int i = 0; i < 4; i++)
#pragma unroll
        for (int j = 0; j < 4; j++)
            acc_kv[i][j] = (f32x4_t){0.f, 0.f, 0.f, 0.f};
    float ks_acc = 0.f;

    const unsigned short* vbase = vT + (size_t)bh * HDIM * SEQ;

    for (int st = 0; st < 4; ++st) {
        int s0 = chunk * 256 + st * 64;
        __syncthreads();   // prior phiT/xs reads complete
        // stage x tile
#pragma unroll
        for (int it = 0; it < 2; ++it) {
            int idx = tid + it * 256;
            int r = idx >> 3, c = (idx & 7) * 8;
            *(u16x8*)&xs[r * 72 + c] =
                *(const u16x8*)(Kx + (size_t)(b * SEQ + s0 + r) * DMODEL + h * HDIM + c);
        }
        __syncthreads();
        // hs
        {
            int token = tid >> 2, seg = (tid & 3) * 16;
            float p = 0.f;
#pragma unroll
            for (int j = 0; j < 16; j++) {
                float xv = b2f(xs[token * 72 + seg + j]);
                p += xv * xv;
            }
            p += __shfl_down(p, 2, 4);
            p += __shfl_down(p, 1, 4);
            if ((tid & 3) == 0) hs[token] = 0.5f * SCALE2 * p;
        }
        // u MFMA (omega B-frags straight from global; L2-hot)
        f32x4_t acc[8];
#pragma unroll
        for (int j = 0; j < 8; j++) acc[j] = (f32x4_t){0.f, 0.f, 0.f, 0.f};
#pragma unroll
        for (int ks = 0; ks < 2; ks++) {
            bf16x8_t af = *(const bf16x8_t*)&xs[(m0 + lm) * 72 + ks * 32 + lk];
#pragma unroll
            for (int j = 0; j < 8; j++) {
                bf16x8_t bfr = *(const bf16x8_t*)(omT + (size_t)(j * 16 + lm) * 64 + ks * 32 + lk);
                acc[j] = __builtin_amdgcn_mfma_f32_16x16x32_bf16(af, bfr, acc[j], 0, 0, 0);
            }
        }
        __syncthreads();   // hs ready
        // epilogue: phi -> phiT LDS [f][m]
#pragma unroll
        for (int j = 0; j < 8; j++) {
            int f = j * 16 + col_l;
#pragma unroll
            for (int r = 0; r < 4; r++) {
                int m = m0 + quad4 + r;
                float u = acc[j][r], hh = hs[m];
                phiT[f * 72 + m]         = f2bu(__expf(u - hh) * FSCALE);
                phiT[(f + 128) * 72 + m] = f2bu(__expf(-u - hh) * FSCALE);
            }
        }
        __syncthreads();   // phiT ready
        // ksum partial: thread owns feature f = tid
        {
            const unsigned short* row = &phiT[tid * 72];
#pragma unroll
            for (int mm = 0; mm < 64; mm += 8) {
                u16x8 v = *(const u16x8*)(row + mm);
#pragma unroll
                for (int e = 0; e < 8; e++) ks_acc += b2f(v[e]);
            }
        }
        // kv MFMA: A = phiT [f][s], B = vT [d][s] (global)
#pragma unroll
        for (int ks = 0; ks < 2; ks++) {
            bf16x8_t af[4], bfr[4];
#pragma unroll
            for (int i = 0; i < 4; i++)
                af[i] = *(const bf16x8_t*)&phiT[(wr + 16 * i + lm) * 72 + ks * 32 + lk];
#pragma unroll
            for (int j = 0; j < 4; j++)
                bfr[j] = *(const bf16x8_t*)(vbase + (size_t)(16 * j + lm) * SEQ + s0 + ks * 32 + lk);
#pragma unroll
            for (int i = 0; i < 4; i++)
#pragma unroll
                for (int j = 0; j < 4; j++)
                    acc_kv[i][j] = __builtin_amdgcn_mfma_f32_16x16x32_bf16(af[i], bfr[j], acc_kv[i][j], 0, 0, 0);
        }
    }

    // write kv partial: layout [chunk][bh][d][f]
    float* kp = kvpart + ((size_t)chunk * BH_TOT + bh) * HDIM * FDIM;
#pragma unroll
    for (int i = 0; i < 4; i++) {
#pragma unroll
        for (int j = 0; j < 4; j++) {
            int d = 16 * j + col_l;
            int f0 = wr + 16 * i + quad4;
            *(f32x4_t*)(kp + (size_t)d * FDIM + f0) = acc_kv[i][j];
        }
    }
    atomicAdd(&ksum[(size_t)bh * FDIM + tid], ks_acc);
}

// ---------------------------------------------------------------- reduce 4 kv partials -> bf16 kvT [bh][d][f]
__global__ __launch_bounds__(256) void reduce_kv_kernel(
    const float* __restrict__ in, unsigned short* __restrict__ out)
{
    const size_t STRIDE = (size_t)BH_TOT * HDIM * FDIM;   // 2M
    size_t i = (size_t)blockIdx.x * 256 + threadIdx.x;
    out[i] = f2bu(in[i] + in[i + STRIDE] + in[i + 2 * STRIDE] + in[i + 3 * STRIDE]);
}

// ---------------------------------------------------------------- fused FAVOR Q-features + attention apply
// grid = BH*16 (64-token tiles). phiQ in LDS [s][f] stride 268 (8B-aligned rows,
// quad-conflict-free epilogue). out[s, h*64+d] = z[s] * phiQ[s,:] . kvT[d,:]
__global__ __launch_bounds__(256) void favor_q_attn_kernel(
    const unsigned short* __restrict__ Qx,   // [N,DM] bf16
    const unsigned short* __restrict__ omT,  // [128][64] bf16 pre-scaled
    const unsigned short* __restrict__ kvT,  // [BH,64,256] bf16
    const float* __restrict__ ksum,          // [BH,256] f32
    unsigned short* __restrict__ outX)       // [N,DM] bf16
{
    const int bid = blockIdx.x;
    const int sc = bid & 15;
    const int bh = bid >> 4;
    const int b = bh >> 3, h = bh & 7;
    const int s0 = sc * 64;
    const int tid = threadIdx.x;
    const int wave = tid >> 6, lane = tid & 63;
    const int lm = lane & 15, lk = (lane >> 4) * 8;
    const int col_l = lane & 15, quad4 = (lane >> 4) * 4;
    const int m0 = wave * 16;

    __shared__ __align__(16) unsigned short xs[64 * 72];      // 9KB
    __shared__ __align__(8)  unsigned short phis[64 * 268];   // 33.5KB [s][f] stride 268
    __shared__ float hs[64];
    __shared__ float zz[64];
    __shared__ float kss[256];

    // stage x tile + ksum
#pragma unroll
    for (int it = 0; it < 2; ++it) {
        int idx = tid + it * 256;
        int r = idx >> 3, c = (idx & 7) * 8;
        *(u16x8*)&xs[r * 72 + c] =
            *(const u16x8*)(Qx + (size_t)(b * SEQ + s0 + r) * DMODEL + h * HDIM + c);
    }
    kss[tid] = ksum[(size_t)bh * FDIM + tid];
    __syncthreads();

    // hs
    {
        int token = tid >> 2, seg = (tid & 3) * 16;
        float p = 0.f;
#pragma unroll
        for (int j = 0; j < 16; j++) {
            float xv = b2f(xs[token * 72 + seg + j]);
            p += xv * xv;
        }
        p += __shfl_down(p, 2, 4);
        p += __shfl_down(p, 1, 4);
        if ((tid & 3) == 0) hs[token] = 0.5f * SCALE2 * p;
    }
    // u MFMA
    f32x4_t acc[8];
#pragma unroll
    for (int j = 0; j < 8; j++) acc[j] = (f32x4_t){0.f, 0.f, 0.f, 0.f};
#pragma unroll
    for (int ks = 0; ks < 2; ks++) {
        bf16x8_t af = *(const bf16x8_t*)&xs[(m0 + lm) * 72 + ks * 32 + lk];
#pragma unroll
        for (int j = 0; j < 8; j++) {
            bf16x8_t bfr = *(const bf16x8_t*)(omT + (size_t)(j * 16 + lm) * 64 + ks * 32 + lk);
            acc[j] = __builtin_amdgcn_mfma_f32_16x16x32_bf16(af, bfr, acc[j], 0, 0, 0);
        }
    }
    __syncthreads();   // hs ready
    // epilogue: phi -> phis [m][f]
#pragma unroll
    for (int j = 0; j < 8; j++) {
        int f = j * 16 + col_l;
#pragma unroll
        for (int r = 0; r < 4; r++) {
            int m = m0 + quad4 + r;
            float u = acc[j][r], hh = hs[m];
            phis[m * 268 + f]       = f2bu(__expf(u - hh) * FSCALE);
            phis[m * 268 + 128 + f] = f2bu(__expf(-u - hh) * FSCALE);
        }
    }
    __syncthreads();   // phis ready
    // z per token (4 threads/token, strided f-chunks of 8)
    {
        int m = tid >> 2, q = tid & 3;
        float zp = 0.f;
#pragma unroll
        for (int kchunk = 0; kchunk < 8; kchunk++) {
            int fp = q * 8 + kchunk * 32;
            u16x4 v0 = *(const u16x4*)&phis[m * 268 + fp];
            u16x4 v1 = *(const u16x4*)&phis[m * 268 + fp + 4];
#pragma unroll
            for (int e = 0; e < 4; e++) {
                zp += b2f(v0[e]) * kss[fp + e];
                zp += b2f(v1[e]) * kss[fp + 4 + e];
            }
        }
        zp += __shfl_down(zp, 2, 4);
        zp += __shfl_down(zp, 1, 4);
        if (q == 0) zz[m] = 1.f / (zp + 1e-6f);
    }
    __syncthreads();   // zz ready
    // attn MFMA: A = phis [s][f] (wave: 16 tokens), B = kvT [d][f] (global)
    const unsigned short* kvbase = kvT + (size_t)bh * HDIM * FDIM;
    f32x4_t acc_o[4];
#pragma unroll
    for (int j = 0; j < 4; j++) acc_o[j] = (f32x4_t){0.f, 0.f, 0.f, 0.f};
#pragma unroll
    for (int k0 = 0; k0 < FDIM; k0 += 32) {
        // 8B-aligned A-frag (row stride 536B)
        bf16x4_t alo = *(const bf16x4_t*)&phis[(m0 + lm) * 268 + k0 + lk];
        bf16x4_t ahi = *(const bf16x4_t*)&phis[(m0 + lm) * 268 + k0 + lk + 4];
        bf16x8_t af;
#pragma unroll
        for (int e = 0; e < 4; e++) { af[e] = alo[e]; af[4 + e] = ahi[e]; }
#pragma unroll
        for (int j = 0; j < 4; j++) {
            bf16x8_t bfr = *(const bf16x8_t*)(kvbase + (size_t)(16 * j + lm) * FDIM + k0 + lk);
            acc_o[j] = __builtin_amdgcn_mfma_f32_16x16x32_bf16(af, bfr, acc_o[j], 0, 0, 0);
        }
    }
    // epilogue: scale by z, store
#pragma unroll
    for (int r = 0; r < 4; r++) {
        int m = m0 + quad4 + r;
        float zv = zz[m];
        int s = s0 + m;
#pragma unroll
        for (int j = 0; j < 4; j++) {
            int d = 16 * j + col_l;
            outX[(size_t)(b * SEQ + s) * DMODEL + h * HDIM + d] = f2bu(acc_o[j][r] * zv);
        }
    }
}

// ---------------------------------------------------------------- residual(bf16) + main(bf16) + LayerNorm -> bf16
template<int HAS_RES>
__global__ __launch_bounds__(512) void add_ln_kernel(
    const unsigned short* __restrict__ res16, const unsigned short* __restrict__ tin16,
    const float* __restrict__ g, const float* __restrict__ bb,
    unsigned short* __restrict__ out16)
{
    int row = blockIdx.x, t = threadIdx.x;
    size_t idx = (size_t)row * DMODEL + t;
    float val = b2f(tin16[idx]);
    if (HAS_RES) val += b2f(res16[idx]);
    float s1 = val, s2 = val * val;
#pragma unroll
    for (int off = 32; off; off >>= 1) {
        s1 += __shfl_down(s1, off, 64);
        s2 += __shfl_down(s2, off, 64);
    }
    __shared__ float w1s[8], w2s[8];
    int wid = t >> 6, lane = t & 63;
    if (lane == 0) { w1s[wid] = s1; w2s[wid] = s2; }
    __syncthreads();
    if (t == 0) {
        float a1 = 0.f, a2 = 0.f;
#pragma unroll
        for (int i = 0; i < 8; i++) { a1 += w1s[i]; a2 += w2s[i]; }
        w1s[0] = a1 * (1.f / DMODEL);
        w2s[0] = a2 * (1.f / DMODEL);
    }
    __syncthreads();
    float m = w1s[0];
    float var = w2s[0] - m * m;
    float r = rsqrtf(var + 1e-5f);
    out16[idx] = f2bu((val - m) * r * g[t] + bb[t]);
}

// ---------------------------------------------------------------- pool stage 1
__global__ __launch_bounds__(256) void pool_part_kernel(
    const unsigned short* __restrict__ h16, float* __restrict__ pbuf)
{
    int blk = blockIdx.x;
    int b = blk >> 4, ch = blk & 15;
    int t = threadIdx.x;
    int d0 = t * 2;
    float a0 = 0.f, a1 = 0.f;
    const unsigned short* base = h16 + ((size_t)(b * SEQ + ch * 64) * DMODEL) + d0;
#pragma unroll 4
    for (int s = 0; s < 64; s++) {
        ushort2 v = *(const ushort2*)(base + (size_t)s * DMODEL);
        a0 += b2f(v.x); a1 += b2f(v.y);
    }
    *(float2*)(pbuf + (size_t)blk * DMODEL + d0) = make_float2(a0, a1);
}

// ---------------------------------------------------------------- pool stage 2 + classify
__global__ __launch_bounds__(512) void cls_kernel(
    const float* __restrict__ pbuf, const float* __restrict__ cls_w,
    const float* __restrict__ cls_b, float* __restrict__ out)
{
    int b = blockIdx.x, t = threadIdx.x;
    float s = 0.f;
#pragma unroll
    for (int c = 0; c < 16; c++) s += pbuf[(size_t)(b * 16 + c) * DMODEL + t];
    __shared__ float pooled[DMODEL];
    pooled[t] = s * (1.f / SEQ);
    __syncthreads();
    if (t < 16) {
        float acc = cls_b[t];
        for (int c = 0; c < DMODEL; c++) acc += pooled[c] * cls_w[c * 16 + t];
        out[b * 16 + t] = acc;
    }
}

// ----------------------------------------------------------------
extern "C" void kernel_launch(void* const* d_in, const int* in_sizes, int n_in,
                              void* d_out, int out_size, void* d_ws, size_t ws_size,
                              hipStream_t stream)
{
    const float* x      = (const float*)d_in[0];
    const float* pos    = (const float*)d_in[1];
    const float* enc_w1 = (const float*)d_in[2];
    const float* enc_b1 = (const float*)d_in[3];
    const float* enc_w2 = (const float*)d_in[4];
    const float* enc_b2 = (const float*)d_in[5];
    const float* enc_g  = (const float*)d_in[6];
    const float* enc_bb = (const float*)d_in[7];
    const float* wq = (const float*)d_in[8];
    const float* bq = (const float*)d_in[9];
    const float* wk = (const float*)d_in[10];
    const float* bk = (const float*)d_in[11];
    const float* wv = (const float*)d_in[12];
    const float* bv = (const float*)d_in[13];
    const float* wo = (const float*)d_in[14];
    const float* bo = (const float*)d_in[15];
    const float* ln1_g = (const float*)d_in[16];
    const float* ln1_b = (const float*)d_in[17];
    const float* w1 = (const float*)d_in[18];
    const float* b1 = (const float*)d_in[19];
    const float* w2 = (const float*)d_in[20];
    const float* b2 = (const float*)d_in[21];
    const float* ln2_g = (const float*)d_in[22];
    const float* ln2_b = (const float*)d_in[23];
    const float* omega = (const float*)d_in[24];
    const float* cls_w = (const float*)d_in[25];
    const float* cls_b = (const float*)d_in[26];
    float* out = (float*)d_out;

    const int N = NTOK;
    const int BH = BH_TOT;

    char* p = (char*)d_ws;
    unsigned short* qb16 = (unsigned short*)p; p += (size_t)N * DMODEL * 2;   // 16MB (also Wo/FFN2 out)
    unsigned short* kb16 = (unsigned short*)p; p += (size_t)N * DMODEL * 2;   // 16MB
    unsigned short* vT16 = (unsigned short*)p; p += (size_t)N * DMODEL * 2;   // 16MB
    unsigned short* h16  = (unsigned short*)p; p += (size_t)N * DMODEL * 2;   // 16MB
    unsigned short* mid16 = (unsigned short*)p; p += (size_t)N * 1024 * 2;    // 32MB
    unsigned short* attn16 = (unsigned short*)p; p += (size_t)N * DMODEL * 2; // 16MB
    float* kvpart = (float*)p;                 p += (size_t)4 * BH * HDIM * FDIM * 4; // 33.5MB
    unsigned short* kvT16 = (unsigned short*)p; p += (size_t)BH * HDIM * FDIM * 2;    // 4MB
    float* ksb = (float*)p;                    p += (size_t)BH * FDIM * 4;    // 128KB
    float* pbuf = (float*)p;                   p += (size_t)BATCH * 16 * DMODEL * 4;  // 512KB
    unsigned short* enc_w2t = (unsigned short*)p; p += (size_t)256 * 512 * 2;
    unsigned short* wqkvt = (unsigned short*)p; p += (size_t)4 * 1536 * 512 * 2;  // 6MB
    unsigned short* wot = (unsigned short*)p;  p += (size_t)4 * 512 * 512 * 2;
    unsigned short* w1t = (unsigned short*)p;  p += (size_t)4 * 512 * 1024 * 2;
    unsigned short* w2t = (unsigned short*)p;  p += (size_t)4 * 1024 * 512 * 2;
    unsigned short* omT = (unsigned short*)p;  p += (size_t)4 * 128 * 64 * 2;

    // ---- weight conversion (batched over layers) ----
    convT_batch_kernel<<<dim3(16, 8, 1), 256, 0, stream>>>(enc_w2, enc_w2t, 256, 512, 0, 0);
    convT_batch_kernel<<<dim3(16, 16, 4), 256, 0, stream>>>(wq, wqkvt,            512, 512, 262144, 786432);
    convT_batch_kernel<<<dim3(16, 16, 4), 256, 0, stream>>>(wk, wqkvt + 262144,   512, 512, 262144, 786432);
    convT_batch_kernel<<<dim3(16, 16, 4), 256, 0, stream>>>(wv, wqkvt + 524288,   512, 512, 262144, 786432);
    convT_batch_kernel<<<dim3(16, 16, 4), 256, 0, stream>>>(wo, wot, 512, 512, 262144, 262144);
    convT_batch_kernel<<<dim3(32, 16, 4), 256, 0, stream>>>(w1, w1t, 512, 1024, 524288, 524288);
    convT_batch_kernel<<<dim3(16, 32, 4), 256, 0, stream>>>(w2, w2t, 1024, 512, 524288, 524288);
    omT_kernel<<<128, 256, 0, stream>>>(omega, omT);

    // ---- encoder ----
    enc1_kernel<<<N, 256, 0, stream>>>(x, pos, enc_w1, enc_b1, mid16);
    gemm_bf16_kernel<0><<<dim3(4, 128), 256, 0, stream>>>(mid16, enc_w2t, enc_b2, qb16, N, 256, 512);
    add_ln_kernel<0><<<N, 512, 0, stream>>>(nullptr, qb16, enc_g, enc_bb, h16);

    // ---- layers ----
    for (int l = 0; l < 4; l++) {
        const unsigned short* omT_l = omT + (size_t)l * 8192;
        gemm_qkv_kernel<<<dim3(12, 128), 256, 0, stream>>>(
            h16, wqkvt + (size_t)l * 786432,
            bq + l * DMODEL, bk + l * DMODEL, bv + l * DMODEL,
            qb16, kb16, vT16);
        zero_kernel<<<BH * FDIM / 256, 256, 0, stream>>>(ksb, BH * FDIM);
        favor_k_kv_kernel<<<BH * 4, 256, 0, stream>>>(kb16, vT16, omT_l, kvpart, ksb);
        reduce_kv_kernel<<<BH * HDIM * FDIM / 256, 256, 0, stream>>>(kvpart, kvT16);
        favor_q_attn_kernel<<<BH * 16, 256, 0, stream>>>(qb16, omT_l, kvT16, ksb, attn16);
        gemm_bf16_kernel<0><<<dim3(4, 128), 256, 0, stream>>>(attn16, wot + (size_t)l * 262144, bo + l * DMODEL, qb16, N, 512, 512);
        add_ln_kernel<1><<<N, 512, 0, stream>>>(h16, qb16, ln1_g + l * DMODEL, ln1_b + l * DMODEL, h16);
        gemm_bf16_kernel<1><<<dim3(8, 128), 256, 0, stream>>>(h16, w1t + (size_t)l * 524288, b1 + l * 1024, mid16, N, 512, 1024);
        gemm_bf16_kernel<0><<<dim3(4, 128), 256, 0, stream>>>(mid16, w2t + (size_t)l * 524288, b2 + l * DMODEL, qb16, N, 1024, 512);
        add_ln_kernel<1><<<N, 512, 0, stream>>>(h16, qb16, ln2_g + l * DMODEL, ln2_b + l * DMODEL, h16);
    }

    // ---- pool + classify ----
    pool_part_kernel<<<BATCH * 16, 256, 0, stream>>>(h16, pbuf);
    cls_kernel<<<BATCH, 512, 0, stream>>>(pbuf, cls_w, cls_b, out);
}

// Round 6
// 1197.946 us; speedup vs baseline: 7.0762x; 1.0504x over previous
//
#include <hip/hip_runtime.h>
#include <hip/hip_bf16.h>
#include <math.h>

// Dims (fixed): B=16, S=1024, N=16384, DM=512, H=8, D=64, F=256, L=4
#define NTOK 16384
#define BATCH 16
#define SEQ 1024
#define DMODEL 512
#define NHEAD 8
#define HDIM 64
#define FDIM 256
#define BH_TOT 128
#define SCALE_QK 0.3535533905932738f   // 64^-0.25
#define SCALE2 0.125f                  // SCALE_QK^2
#define FSCALE 0.0625f                 // 256^-0.5

typedef __bf16 bf16x8_t __attribute__((ext_vector_type(8)));
typedef float f32x4_t  __attribute__((ext_vector_type(4)));
typedef unsigned short u16x8 __attribute__((ext_vector_type(8)));
typedef unsigned short u16x4 __attribute__((ext_vector_type(4)));
typedef const __attribute__((address_space(1))) char* gas_t;
typedef __attribute__((address_space(3))) char* las_t;

__device__ __forceinline__ float b2f(unsigned short u) {
    union { unsigned int i; float f; } c; c.i = ((unsigned int)u) << 16; return c.f;
}
__device__ __forceinline__ unsigned short f2bu(float f) {
    __hip_bfloat16 h = __float2bfloat16(f);
    return *(unsigned short*)&h;
}
__device__ __forceinline__ bf16x8_t u2b8(u16x8 u) {
    union { u16x8 a; bf16x8_t b; } c; c.a = u; return c.b;
}

// ---------------------------------------------------------------- zero
__global__ void zero_kernel(float* __restrict__ p, int n) {
    int i = blockIdx.x * 256 + threadIdx.x;
    if (i < n) p[i] = 0.f;
}

// ---------------------------------------------------------------- batched weight convert+transpose: W[K,N] f32 -> Wt[N,K] bf16, grid.z = layer
__global__ __launch_bounds__(256) void convT_batch_kernel(
    const float* __restrict__ W, unsigned short* __restrict__ Wt, int K, int N,
    size_t in_lstride, size_t out_lstride)
{
    int l = blockIdx.z;
    W  += (size_t)l * in_lstride;
    Wt += (size_t)l * out_lstride;
    __shared__ float tile[32][33];
    int k0 = blockIdx.y * 32, n0 = blockIdx.x * 32;
    int t = threadIdx.x;
    int r = t >> 3, c4 = (t & 7) * 4;
    float4 v = *(const float4*)(W + (size_t)(k0 + r) * N + n0 + c4);
    tile[r][c4 + 0] = v.x; tile[r][c4 + 1] = v.y;
    tile[r][c4 + 2] = v.z; tile[r][c4 + 3] = v.w;
    __syncthreads();
    ushort4 o;
    o.x = f2bu(tile[c4 + 0][r]); o.y = f2bu(tile[c4 + 1][r]);
    o.z = f2bu(tile[c4 + 2][r]); o.w = f2bu(tile[c4 + 3][r]);
    *(ushort4*)(Wt + (size_t)(n0 + r) * K + k0 + c4) = o;
}

// ---------------------------------------------------------------- omega transpose+scale
__global__ __launch_bounds__(256) void omT_kernel(
    const float* __restrict__ om, unsigned short* __restrict__ omT)
{
    int i = blockIdx.x * 256 + threadIdx.x;   // over 4*8192
    int l = i >> 13, rem = i & 8191;
    int f = rem >> 6, d = rem & 63;
    omT[(size_t)l * 8192 + f * 64 + d] = f2bu(om[(size_t)l * 8192 + d * 128 + f] * SCALE_QK);
}

// ---------------------------------------------------------------- encoder stage 1
__global__ __launch_bounds__(256) void enc1_kernel(
    const float* __restrict__ x, const float* __restrict__ pos,
    const float* __restrict__ w1, const float* __restrict__ b1,
    unsigned short* __restrict__ mid)
{
    int row = blockIdx.x, t = threadIdx.x;
    __shared__ float in6[6];
    if (t < 3) in6[t] = x[row * 3 + t];
    else if (t < 6) in6[t] = pos[row * 3 + (t - 3)];
    __syncthreads();
    float acc = b1[t];
#pragma unroll
    for (int j = 0; j < 6; j++) acc += in6[j] * w1[j * 256 + t];
    mid[(size_t)row * 256 + t] = f2bu(fmaxf(acc, 0.f));
}

// ---------------------------------------------------------------- bf16 MFMA GEMM with XCD swizzle: C = [relu](A @ Bt^T + bias) -> bf16
// 1D grid of nx*ny blocks; ny (=M/128) must be divisible by 8.
// row-tile -> XCD binding: all nx col-blocks of a row land on one XCD.
template<int RELU>
__global__ __launch_bounds__(256) void gemm_bf16_kernel(
    const unsigned short* __restrict__ A, const unsigned short* __restrict__ Bt,
    const float* __restrict__ bias, unsigned short* __restrict__ C,
    int M, int K, int Nc, int nx)
{
    __shared__ __align__(16) unsigned short As[128 * 32];
    __shared__ __align__(16) unsigned short Bs[128 * 32];
    const int tid = threadIdx.x;
    const int id = blockIdx.x;
    const int xcd = id & 7, slot = id >> 3;
    const int bm = ((slot / nx) * 8 + xcd) * 128;
    const int bn = (slot % nx) * 128;
    const int wave = tid >> 6, lane = tid & 63;
    const int wr = (wave >> 1) * 64, wc = (wave & 1) * 64;
    const int lm = lane & 15, lk = (lane >> 4) * 8;

    f32x4_t acc[4][4];
#pragma unroll
    for (int i = 0; i < 4; i++)
#pragma unroll
        for (int j = 0; j < 4; j++)
            acc[i][j] = (f32x4_t){0.f, 0.f, 0.f, 0.f};

    for (int k0 = 0; k0 < K; k0 += 32) {
#pragma unroll
        for (int it = 0; it < 2; ++it) {
            int t = tid + it * 256;
            const unsigned short* gp = A + (size_t)(bm + (t >> 2)) * K + k0 + (t & 3) * 8;
            __builtin_amdgcn_global_load_lds((gas_t)(const char*)gp,
                (las_t)((char*)As + t * 16), 16, 0, 0);
        }
#pragma unroll
        for (int it = 0; it < 2; ++it) {
            int t = tid + it * 256;
            const unsigned short* gp = Bt + (size_t)(bn + (t >> 2)) * K + k0 + (t & 3) * 8;
            __builtin_amdgcn_global_load_lds((gas_t)(const char*)gp,
                (las_t)((char*)Bs + t * 16), 16, 0, 0);
        }
        __syncthreads();
        bf16x8_t af[4], bfr[4];
#pragma unroll
        for (int i = 0; i < 4; i++)
            af[i] = *(const bf16x8_t*)(As + (size_t)(wr + 16 * i + lm) * 32 + lk);
#pragma unroll
        for (int j = 0; j < 4; j++)
            bfr[j] = *(const bf16x8_t*)(Bs + (size_t)(wc + 16 * j + lm) * 32 + lk);
#pragma unroll
        for (int i = 0; i < 4; i++)
#pragma unroll
            for (int j = 0; j < 4; j++)
                acc[i][j] = __builtin_amdgcn_mfma_f32_16x16x32_bf16(af[i], bfr[j], acc[i][j], 0, 0, 0);
        __syncthreads();
    }

    const int col_l = lane & 15;
    const int row_q = (lane >> 4) * 4;
#pragma unroll
    for (int i = 0; i < 4; i++) {
#pragma unroll
        for (int j = 0; j < 4; j++) {
            int gn = bn + wc + 16 * j + col_l;
            float bsv = bias[gn];
            int gm0 = bm + wr + 16 * i + row_q;
#pragma unroll
            for (int r = 0; r < 4; r++) {
                float v = acc[i][j][r] + bsv;
                if (RELU) v = fmaxf(v, 0.f);
                C[(size_t)(gm0 + r) * Nc + gn] = f2bu(v);
            }
        }
    }
}

// ---------------------------------------------------------------- fused QKV GEMM (XCD swizzle, nx=12): A[M,512] @ WqkvT[1536,512]^T
__global__ __launch_bounds__(256) void gemm_qkv_kernel(
    const unsigned short* __restrict__ A, const unsigned short* __restrict__ Bt,
    const float* __restrict__ bq, const float* __restrict__ bk, const float* __restrict__ bv,
    unsigned short* __restrict__ Q, unsigned short* __restrict__ Kk,
    unsigned short* __restrict__ vT)
{
    __shared__ __align__(16) unsigned short As[128 * 32];
    __shared__ __align__(16) unsigned short Bs[128 * 32];
    const int tid = threadIdx.x;
    const int id = blockIdx.x;
    const int xcd = id & 7, slot = id >> 3;
    const int bm = ((slot / 12) * 8 + xcd) * 128;
    const int bn = (slot % 12) * 128;
    const int wave = tid >> 6, lane = tid & 63;
    const int wr = (wave >> 1) * 64, wc = (wave & 1) * 64;
    const int lm = lane & 15, lk = (lane >> 4) * 8;
    const int K = DMODEL;

    f32x4_t acc[4][4];
#pragma unroll
    for (int i = 0; i < 4; i++)
#pragma unroll
        for (int j = 0; j < 4; j++)
            acc[i][j] = (f32x4_t){0.f, 0.f, 0.f, 0.f};

    for (int k0 = 0; k0 < K; k0 += 32) {
#pragma unroll
        for (int it = 0; it < 2; ++it) {
            int t = tid + it * 256;
            const unsigned short* gp = A + (size_t)(bm + (t >> 2)) * K + k0 + (t & 3) * 8;
            __builtin_amdgcn_global_load_lds((gas_t)(const char*)gp,
                (las_t)((char*)As + t * 16), 16, 0, 0);
        }
#pragma unroll
        for (int it = 0; it < 2; ++it) {
            int t = tid + it * 256;
            const unsigned short* gp = Bt + (size_t)(bn + (t >> 2)) * K + k0 + (t & 3) * 8;
            __builtin_amdgcn_global_load_lds((gas_t)(const char*)gp,
                (las_t)((char*)Bs + t * 16), 16, 0, 0);
        }
        __syncthreads();
        bf16x8_t af[4], bfr[4];
#pragma unroll
        for (int i = 0; i < 4; i++)
            af[i] = *(const bf16x8_t*)(As + (size_t)(wr + 16 * i + lm) * 32 + lk);
#pragma unroll
        for (int j = 0; j < 4; j++)
            bfr[j] = *(const bf16x8_t*)(Bs + (size_t)(wc + 16 * j + lm) * 32 + lk);
#pragma unroll
        for (int i = 0; i < 4; i++)
#pragma unroll
            for (int j = 0; j < 4; j++)
                acc[i][j] = __builtin_amdgcn_mfma_f32_16x16x32_bf16(af[i], bfr[j], acc[i][j], 0, 0, 0);
        __syncthreads();
    }

    const int sect = bn >> 9;
    const float* bias = (sect == 0) ? bq : (sect == 1) ? bk : bv;
    unsigned short* rowout = (sect == 0) ? Q : Kk;
    const int cb = bn & 511;
    const int col_l = lane & 15;
    const int row_q = (lane >> 4) * 4;
#pragma unroll
    for (int i = 0; i < 4; i++) {
#pragma unroll
        for (int j = 0; j < 4; j++) {
            int cn = cb + wc + 16 * j + col_l;
            float bsv = bias[cn];
            int gm0 = bm + wr + 16 * i + row_q;
            if (sect < 2) {
#pragma unroll
                for (int r = 0; r < 4; r++)
                    rowout[(size_t)(gm0 + r) * DMODEL + cn] = f2bu(acc[i][j][r] + bsv);
            } else {
                int bb_ = gm0 >> 10, ss = gm0 & 1023;
                int hh_ = cn >> 6, dd = cn & 63;
                u16x4 o4;
#pragma unroll
                for (int r = 0; r < 4; r++) o4[r] = f2bu(acc[i][j][r] + bsv);
                *(u16x4*)(vT + (((size_t)(bb_ * NHEAD + hh_) * HDIM + dd) * SEQ + ss)) = o4;
            }
        }
    }
}

// ---------------------------------------------------------------- fused FAVOR K-features + kv accumulate (v2: global A-frags, no xs)
// grid = BH*4 (256-token chunks); 4 subtiles of 64 tokens.
__global__ __launch_bounds__(256) void favor_k_kv_kernel(
    const unsigned short* __restrict__ Kx,   // [N,DM] bf16
    const unsigned short* __restrict__ vT,   // [BH,64,1024] bf16
    const unsigned short* __restrict__ omT,  // [128][64] bf16 pre-scaled
    float* __restrict__ kvpart,
    float* __restrict__ ksum)
{
    const int bid = blockIdx.x;
    const int chunk = bid & 3;
    const int bh = bid >> 2;
    const int b = bh >> 3, h = bh & 7;
    const int tid = threadIdx.x;
    const int wave = tid >> 6, lane = tid & 63;
    const int lm = lane & 15, q = lane >> 4, lk = q * 8;
    const int quad4 = q * 4;
    const int wr = wave * 64;       // f-rows for kv MFMA
    const int m0 = wave * 16;       // tokens for u MFMA

    __shared__ __align__(16) unsigned short phiT[256 * 72];  // 36 KB [f][m]
    __shared__ float hsh[64];

    f32x4_t acc_kv[4][4];
#pragma unroll
    for (int i = 0; i < 4; i++)
#pragma unroll
        for (int j = 0; j < 4; j++)
            acc_kv[i][j] = (f32x4_t){0.f, 0.f, 0.f, 0.f};
    float ks_acc = 0.f;

    const unsigned short* vbase = vT + (size_t)bh * HDIM * SEQ;

    for (int st = 0; st < 4; ++st) {
        int s0 = chunk * 256 + st * 64;
        // A-frags from global
        const unsigned short* krow = Kx + (size_t)(b * SEQ + s0 + m0 + lm) * DMODEL + h * HDIM;
        u16x8 xu0 = *(const u16x8*)(krow + lk);
        u16x8 xu1 = *(const u16x8*)(krow + 32 + lk);
        float p = 0.f;
#pragma unroll
        for (int e = 0; e < 8; e++) {
            float a = b2f(xu0[e]), c = b2f(xu1[e]);
            p += a * a + c * c;
        }
        p += __shfl_xor(p, 16, 64);
        p += __shfl_xor(p, 32, 64);
        __syncthreads();   // prior phiT/hsh consumers done
        if (q == 0) hsh[m0 + lm] = 0.5f * SCALE2 * p;
        // u MFMA
        f32x4_t acc[8];
#pragma unroll
        for (int j = 0; j < 8; j++) acc[j] = (f32x4_t){0.f, 0.f, 0.f, 0.f};
        bf16x8_t af0 = u2b8(xu0), af1 = u2b8(xu1);
#pragma unroll
        for (int j = 0; j < 8; j++) {
            bf16x8_t b0 = *(const bf16x8_t*)(omT + (size_t)(j * 16 + lm) * 64 + lk);
            acc[j] = __builtin_amdgcn_mfma_f32_16x16x32_bf16(af0, b0, acc[j], 0, 0, 0);
            bf16x8_t b1 = *(const bf16x8_t*)(omT + (size_t)(j * 16 + lm) * 64 + 32 + lk);
            acc[j] = __builtin_amdgcn_mfma_f32_16x16x32_bf16(af1, b1, acc[j], 0, 0, 0);
        }
        __syncthreads();   // hsh ready
        // epilogue: phi -> phiT [f][m]
#pragma unroll
        for (int j = 0; j < 8; j++) {
            int f = j * 16 + lm;
#pragma unroll
            for (int r = 0; r < 4; r++) {
                int m = m0 + quad4 + r;
                float u = acc[j][r], hh = hsh[m];
                phiT[f * 72 + m]         = f2bu(__expf(u - hh) * FSCALE);
                phiT[(f + 128) * 72 + m] = f2bu(__expf(-u - hh) * FSCALE);
            }
        }
        __syncthreads();   // phiT ready
        // ksum partial: thread owns feature f = tid
        {
            const unsigned short* row = &phiT[tid * 72];
#pragma unroll
            for (int mm = 0; mm < 64; mm += 8) {
                u16x8 v = *(const u16x8*)(row + mm);
#pragma unroll
                for (int e = 0; e < 8; e++) ks_acc += b2f(v[e]);
            }
        }
        // kv MFMA: A = phiT [f][s], B = vT [d][s] (global)
#pragma unroll
        for (int ks = 0; ks < 2; ks++) {
            bf16x8_t af[4], bfr[4];
#pragma unroll
            for (int i = 0; i < 4; i++)
                af[i] = *(const bf16x8_t*)&phiT[(wr + 16 * i + lm) * 72 + ks * 32 + lk];
#pragma unroll
            for (int j = 0; j < 4; j++)
                bfr[j] = *(const bf16x8_t*)(vbase + (size_t)(16 * j + lm) * SEQ + s0 + ks * 32 + lk);
#pragma unroll
            for (int i = 0; i < 4; i++)
#pragma unroll
                for (int j = 0; j < 4; j++)
                    acc_kv[i][j] = __builtin_amdgcn_mfma_f32_16x16x32_bf16(af[i], bfr[j], acc_kv[i][j], 0, 0, 0);
        }
    }

    // write kv partial: layout [chunk][bh][d][f]
    float* kp = kvpart + ((size_t)chunk * BH_TOT + bh) * HDIM * FDIM;
#pragma unroll
    for (int i = 0; i < 4; i++) {
#pragma unroll
        for (int j = 0; j < 4; j++) {
            int d = 16 * j + lm;
            int f0 = wr + 16 * i + quad4;
            *(f32x4_t*)(kp + (size_t)d * FDIM + f0) = acc_kv[i][j];
        }
    }
    atomicAdd(&ksum[(size_t)bh * FDIM + tid], ks_acc);
}

// ---------------------------------------------------------------- reduce 4 kv partials -> bf16 kvT [bh][d][f]
__global__ __launch_bounds__(256) void reduce_kv_kernel(
    const float* __restrict__ in, unsigned short* __restrict__ out)
{
    const size_t STRIDE = (size_t)BH_TOT * HDIM * FDIM;   // 2M
    size_t i = (size_t)blockIdx.x * 256 + threadIdx.x;
    out[i] = f2bu(in[i] + in[i + STRIDE] + in[i + 2 * STRIDE] + in[i + 3 * STRIDE]);
}

// ---------------------------------------------------------------- fused FAVOR Q-features + attention (v2: two-pass phi, reg-z, ~19KB LDS)
// grid = BH*16 (64-token tiles).
__global__ __launch_bounds__(256) void favor_q_attn_kernel(
    const unsigned short* __restrict__ Qx,   // [N,DM] bf16
    const unsigned short* __restrict__ omT,  // [128][64] bf16 pre-scaled
    const unsigned short* __restrict__ kvT,  // [BH,64,256] bf16
    const float* __restrict__ ksum,          // [BH,256] f32
    unsigned short* __restrict__ outX)       // [N,DM] bf16
{
    const int bid = blockIdx.x;
    const int sc = bid & 15;
    const int bh = bid >> 4;
    const int b = bh >> 3, h = bh & 7;
    const int s0 = sc * 64;
    const int tid = threadIdx.x;
    const int wave = tid >> 6, lane = tid & 63;
    const int lm = lane & 15, q = lane >> 4, lk = q * 8;
    const int quad4 = q * 4;
    const int m0 = wave * 16;

    __shared__ __align__(16) unsigned short phis[64 * 136];  // 17 KB [m][f-half]
    __shared__ float kss[256];
    __shared__ float hsh[64];
    __shared__ float zzs[64];

    kss[tid] = ksum[(size_t)bh * FDIM + tid];

    // A-frags from global
    const unsigned short* qrow = Qx + (size_t)(b * SEQ + s0 + m0 + lm) * DMODEL + h * HDIM;
    u16x8 xu0 = *(const u16x8*)(qrow + lk);
    u16x8 xu1 = *(const u16x8*)(qrow + 32 + lk);
    float p = 0.f;
#pragma unroll
    for (int e = 0; e < 8; e++) {
        float a = b2f(xu0[e]), c = b2f(xu1[e]);
        p += a * a + c * c;
    }
    p += __shfl_xor(p, 16, 64);
    p += __shfl_xor(p, 32, 64);
    if (q == 0) hsh[m0 + lm] = 0.5f * SCALE2 * p;

    // u MFMA
    f32x4_t acc[8];
#pragma unroll
    for (int j = 0; j < 8; j++) acc[j] = (f32x4_t){0.f, 0.f, 0.f, 0.f};
    bf16x8_t af0 = u2b8(xu0), af1 = u2b8(xu1);
#pragma unroll
    for (int j = 0; j < 8; j++) {
        bf16x8_t b0 = *(const bf16x8_t*)(omT + (size_t)(j * 16 + lm) * 64 + lk);
        acc[j] = __builtin_amdgcn_mfma_f32_16x16x32_bf16(af0, b0, acc[j], 0, 0, 0);
        bf16x8_t b1 = *(const bf16x8_t*)(omT + (size_t)(j * 16 + lm) * 64 + 32 + lk);
        acc[j] = __builtin_amdgcn_mfma_f32_16x16x32_bf16(af1, b1, acc[j], 0, 0, 0);
    }
    __syncthreads();   // hsh + kss ready

    // pass-1 epilogue: write phi+ to LDS, z fully in registers
    float zp[4] = {0.f, 0.f, 0.f, 0.f};
#pragma unroll
    for (int j = 0; j < 8; j++) {
        int f = j * 16 + lm;
        float ksp = kss[f], ksm = kss[128 + f];
#pragma unroll
        for (int r = 0; r < 4; r++) {
            int m = m0 + quad4 + r;
            float u = acc[j][r], hh = hsh[m];
            float pp = __expf(u - hh) * FSCALE;
            float pm = __expf(-u - hh) * FSCALE;
            phis[m * 136 + f] = f2bu(pp);
            zp[r] += pp * ksp + pm * ksm;
        }
    }
#pragma unroll
    for (int off = 1; off < 16; off <<= 1) {
        zp[0] += __shfl_xor(zp[0], off, 64);
        zp[1] += __shfl_xor(zp[1], off, 64);
        zp[2] += __shfl_xor(zp[2], off, 64);
        zp[3] += __shfl_xor(zp[3], off, 64);
    }
    if (lm == 0) {
#pragma unroll
        for (int r = 0; r < 4; r++)
            zzs[m0 + quad4 + r] = 1.f / (zp[r] + 1e-6f);
    }
    __syncthreads();   // phi+ ready (all waves)

    const unsigned short* kvbase = kvT + (size_t)bh * HDIM * FDIM;
    f32x4_t acc_o[4];
#pragma unroll
    for (int j = 0; j < 4; j++) acc_o[j] = (f32x4_t){0.f, 0.f, 0.f, 0.f};
    // pass 1: features [0,128)
#pragma unroll
    for (int k0 = 0; k0 < 128; k0 += 32) {
        bf16x8_t af = *(const bf16x8_t*)&phis[(m0 + lm) * 136 + k0 + lk];
#pragma unroll
        for (int j = 0; j < 4; j++) {
            bf16x8_t bfr = *(const bf16x8_t*)(kvbase + (size_t)(16 * j + lm) * FDIM + k0 + lk);
            acc_o[j] = __builtin_amdgcn_mfma_f32_16x16x32_bf16(af, bfr, acc_o[j], 0, 0, 0);
        }
    }
    __syncthreads();   // pass-1 reads done
    // pass-2 epilogue: overwrite with phi-
#pragma unroll
    for (int j = 0; j < 8; j++) {
        int f = j * 16 + lm;
#pragma unroll
        for (int r = 0; r < 4; r++) {
            int m = m0 + quad4 + r;
            phis[m * 136 + f] = f2bu(__expf(-acc[j][r] - hsh[m]) * FSCALE);
        }
    }
    __syncthreads();   // phi- ready
    // pass 2: features [128,256)
#pragma unroll
    for (int k0 = 0; k0 < 128; k0 += 32) {
        bf16x8_t af = *(const bf16x8_t*)&phis[(m0 + lm) * 136 + k0 + lk];
#pragma unroll
        for (int j = 0; j < 4; j++) {
            bf16x8_t bfr = *(const bf16x8_t*)(kvbase + (size_t)(16 * j + lm) * FDIM + 128 + k0 + lk);
            acc_o[j] = __builtin_amdgcn_mfma_f32_16x16x32_bf16(af, bfr, acc_o[j], 0, 0, 0);
        }
    }
    // epilogue: scale by z, store
#pragma unroll
    for (int r = 0; r < 4; r++) {
        int m = m0 + quad4 + r;
        float zv = zzs[m];
        int s = s0 + m;
#pragma unroll
        for (int j = 0; j < 4; j++) {
            int d = 16 * j + lm;
            outX[(size_t)(b * SEQ + s) * DMODEL + h * HDIM + d] = f2bu(acc_o[j][r] * zv);
        }
    }
}

// ---------------------------------------------------------------- residual(bf16) + main(bf16) + LayerNorm -> bf16
template<int HAS_RES>
__global__ __launch_bounds__(512) void add_ln_kernel(
    const unsigned short* __restrict__ res16, const unsigned short* __restrict__ tin16,
    const float* __restrict__ g, const float* __restrict__ bb,
    unsigned short* __restrict__ out16)
{
    int row = blockIdx.x, t = threadIdx.x;
    size_t idx = (size_t)row * DMODEL + t;
    float val = b2f(tin16[idx]);
    if (HAS_RES) val += b2f(res16[idx]);
    float s1 = val, s2 = val * val;
#pragma unroll
    for (int off = 32; off; off >>= 1) {
        s1 += __shfl_down(s1, off, 64);
        s2 += __shfl_down(s2, off, 64);
    }
    __shared__ float w1s[8], w2s[8];
    int wid = t >> 6, lane = t & 63;
    if (lane == 0) { w1s[wid] = s1; w2s[wid] = s2; }
    __syncthreads();
    if (t == 0) {
        float a1 = 0.f, a2 = 0.f;
#pragma unroll
        for (int i = 0; i < 8; i++) { a1 += w1s[i]; a2 += w2s[i]; }
        w1s[0] = a1 * (1.f / DMODEL);
        w2s[0] = a2 * (1.f / DMODEL);
    }
    __syncthreads();
    float m = w1s[0];
    float var = w2s[0] - m * m;
    float r = rsqrtf(var + 1e-5f);
    out16[idx] = f2bu((val - m) * r * g[t] + bb[t]);
}

// ---------------------------------------------------------------- pool stage 1
__global__ __launch_bounds__(256) void pool_part_kernel(
    const unsigned short* __restrict__ h16, float* __restrict__ pbuf)
{
    int blk = blockIdx.x;
    int b = blk >> 4, ch = blk & 15;
    int t = threadIdx.x;
    int d0 = t * 2;
    float a0 = 0.f, a1 = 0.f;
    const unsigned short* base = h16 + ((size_t)(b * SEQ + ch * 64) * DMODEL) + d0;
#pragma unroll 4
    for (int s = 0; s < 64; s++) {
        ushort2 v = *(const ushort2*)(base + (size_t)s * DMODEL);
        a0 += b2f(v.x); a1 += b2f(v.y);
    }
    *(float2*)(pbuf + (size_t)blk * DMODEL + d0) = make_float2(a0, a1);
}

// ---------------------------------------------------------------- pool stage 2 + classify
__global__ __launch_bounds__(512) void cls_kernel(
    const float* __restrict__ pbuf, const float* __restrict__ cls_w,
    const float* __restrict__ cls_b, float* __restrict__ out)
{
    int b = blockIdx.x, t = threadIdx.x;
    float s = 0.f;
#pragma unroll
    for (int c = 0; c < 16; c++) s += pbuf[(size_t)(b * 16 + c) * DMODEL + t];
    __shared__ float pooled[DMODEL];
    pooled[t] = s * (1.f / SEQ);
    __syncthreads();
    if (t < 16) {
        float acc = cls_b[t];
        for (int c = 0; c < DMODEL; c++) acc += pooled[c] * cls_w[c * 16 + t];
        out[b * 16 + t] = acc;
    }
}

// ----------------------------------------------------------------
extern "C" void kernel_launch(void* const* d_in, const int* in_sizes, int n_in,
                              void* d_out, int out_size, void* d_ws, size_t ws_size,
                              hipStream_t stream)
{
    const float* x      = (const float*)d_in[0];
    const float* pos    = (const float*)d_in[1];
    const float* enc_w1 = (const float*)d_in[2];
    const float* enc_b1 = (const float*)d_in[3];
    const float* enc_w2 = (const float*)d_in[4];
    const float* enc_b2 = (const float*)d_in[5];
    const float* enc_g  = (const float*)d_in[6];
    const float* enc_bb = (const float*)d_in[7];
    const float* wq = (const float*)d_in[8];
    const float* bq = (const float*)d_in[9];
    const float* wk = (const float*)d_in[10];
    const float* bk = (const float*)d_in[11];
    const float* wv = (const float*)d_in[12];
    const float* bv = (const float*)d_in[13];
    const float* wo = (const float*)d_in[14];
    const float* bo = (const float*)d_in[15];
    const float* ln1_g = (const float*)d_in[16];
    const float* ln1_b = (const float*)d_in[17];
    const float* w1 = (const float*)d_in[18];
    const float* b1 = (const float*)d_in[19];
    const float* w2 = (const float*)d_in[20];
    const float* b2 = (const float*)d_in[21];
    const float* ln2_g = (const float*)d_in[22];
    const float* ln2_b = (const float*)d_in[23];
    const float* omega = (const float*)d_in[24];
    const float* cls_w = (const float*)d_in[25];
    const float* cls_b = (const float*)d_in[26];
    float* out = (float*)d_out;

    const int N = NTOK;
    const int BH = BH_TOT;

    char* p = (char*)d_ws;
    unsigned short* qb16 = (unsigned short*)p; p += (size_t)N * DMODEL * 2;   // 16MB (also Wo/FFN2 out)
    unsigned short* kb16 = (unsigned short*)p; p += (size_t)N * DMODEL * 2;   // 16MB
    unsigned short* vT16 = (unsigned short*)p; p += (size_t)N * DMODEL * 2;   // 16MB
    unsigned short* h16  = (unsigned short*)p; p += (size_t)N * DMODEL * 2;   // 16MB
    unsigned short* mid16 = (unsigned short*)p; p += (size_t)N * 1024 * 2;    // 32MB
    unsigned short* attn16 = (unsigned short*)p; p += (size_t)N * DMODEL * 2; // 16MB
    float* kvpart = (float*)p;                 p += (size_t)4 * BH * HDIM * FDIM * 4; // 33.5MB
    unsigned short* kvT16 = (unsigned short*)p; p += (size_t)BH * HDIM * FDIM * 2;    // 4MB
    float* ksb = (float*)p;                    p += (size_t)BH * FDIM * 4;    // 128KB
    float* pbuf = (float*)p;                   p += (size_t)BATCH * 16 * DMODEL * 4;  // 512KB
    unsigned short* enc_w2t = (unsigned short*)p; p += (size_t)256 * 512 * 2;
    unsigned short* wqkvt = (unsigned short*)p; p += (size_t)4 * 1536 * 512 * 2;  // 6MB
    unsigned short* wot = (unsigned short*)p;  p += (size_t)4 * 512 * 512 * 2;
    unsigned short* w1t = (unsigned short*)p;  p += (size_t)4 * 512 * 1024 * 2;
    unsigned short* w2t = (unsigned short*)p;  p += (size_t)4 * 1024 * 512 * 2;
    unsigned short* omT = (unsigned short*)p;  p += (size_t)4 * 128 * 64 * 2;

    // ---- weight conversion (batched over layers) ----
    convT_batch_kernel<<<dim3(16, 8, 1), 256, 0, stream>>>(enc_w2, enc_w2t, 256, 512, 0, 0);
    convT_batch_kernel<<<dim3(16, 16, 4), 256, 0, stream>>>(wq, wqkvt,            512, 512, 262144, 786432);
    convT_batch_kernel<<<dim3(16, 16, 4), 256, 0, stream>>>(wk, wqkvt + 262144,   512, 512, 262144, 786432);
    convT_batch_kernel<<<dim3(16, 16, 4), 256, 0, stream>>>(wv, wqkvt + 524288,   512, 512, 262144, 786432);
    convT_batch_kernel<<<dim3(16, 16, 4), 256, 0, stream>>>(wo, wot, 512, 512, 262144, 262144);
    convT_batch_kernel<<<dim3(32, 16, 4), 256, 0, stream>>>(w1, w1t, 512, 1024, 524288, 524288);
    convT_batch_kernel<<<dim3(16, 32, 4), 256, 0, stream>>>(w2, w2t, 1024, 512, 524288, 524288);
    omT_kernel<<<128, 256, 0, stream>>>(omega, omT);

    // ---- encoder ----
    enc1_kernel<<<N, 256, 0, stream>>>(x, pos, enc_w1, enc_b1, mid16);
    gemm_bf16_kernel<0><<<4 * 128, 256, 0, stream>>>(mid16, enc_w2t, enc_b2, qb16, N, 256, 512, 4);
    add_ln_kernel<0><<<N, 512, 0, stream>>>(nullptr, qb16, enc_g, enc_bb, h16);

    // ---- layers ----
    for (int l = 0; l < 4; l++) {
        const unsigned short* omT_l = omT + (size_t)l * 8192;
        gemm_qkv_kernel<<<12 * 128, 256, 0, stream>>>(
            h16, wqkvt + (size_t)l * 786432,
            bq + l * DMODEL, bk + l * DMODEL, bv + l * DMODEL,
            qb16, kb16, vT16);
        zero_kernel<<<BH * FDIM / 256, 256, 0, stream>>>(ksb, BH * FDIM);
        favor_k_kv_kernel<<<BH * 4, 256, 0, stream>>>(kb16, vT16, omT_l, kvpart, ksb);
        reduce_kv_kernel<<<BH * HDIM * FDIM / 256, 256, 0, stream>>>(kvpart, kvT16);
        favor_q_attn_kernel<<<BH * 16, 256, 0, stream>>>(qb16, omT_l, kvT16, ksb, attn16);
        gemm_bf16_kernel<0><<<4 * 128, 256, 0, stream>>>(attn16, wot + (size_t)l * 262144, bo + l * DMODEL, qb16, N, 512, 512, 4);
        add_ln_kernel<1><<<N, 512, 0, stream>>>(h16, qb16, ln1_g + l * DMODEL, ln1_b + l * DMODEL, h16);
        gemm_bf16_kernel<1><<<8 * 128, 256, 0, stream>>>(h16, w1t + (size_t)l * 524288, b1 + l * 1024, mid16, N, 512, 1024, 8);
        gemm_bf16_kernel<0><<<4 * 128, 256, 0, stream>>>(mid16, w2t + (size_t)l * 524288, b2 + l * DMODEL, qb16, N, 1024, 512, 4);
        add_ln_kernel<1><<<N, 512, 0, stream>>>(h16, qb16, ln2_g + l * DMODEL, ln2_b + l * DMODEL, h16);
    }

    // ---- pool + classify ----
    pool_part_kernel<<<BATCH * 16, 256, 0, stream>>>(h16, pbuf);
    cls_kernel<<<BATCH, 512, 0, stream>>>(pbuf, cls_w, cls_b, out);
}